// Round 5
// baseline (253.322 us; speedup 1.0000x reference)
//
#include <hip/hip_runtime.h>

typedef unsigned char u8;
typedef unsigned short u16;
typedef unsigned int u32;
typedef unsigned long long u64;
typedef long long i64;
typedef __attribute__((ext_vector_type(16))) float floatx16;

#define BN 8192
#define DIM 256
#define NSPLIT 8
#define KPS (BN / NSPLIT)   // 1024 keys per split
#define BKN 32              // keys per iter
#define NIT (KPS / BKN)     // 32 iters
#define NQB (BN / 128)      // 64 q-blocks

__device__ __forceinline__ u16 f2bf(float x) {
    u32 u = __builtin_bit_cast(u32, x);
    u = (u + 0x7fffu + ((u >> 16) & 1u)) >> 16;
    return (u16)u;
}
__device__ __forceinline__ float bf2f(u16 h) {
    return __builtin_bit_cast(float, (u32)h << 16);
}
__device__ __forceinline__ u64 pack4bf(float a, float b, float c, float d) {
    return (u64)f2bf(a) | ((u64)f2bf(b) << 16) | ((u64)f2bf(c) << 32) | ((u64)f2bf(d) << 48);
}
__device__ __forceinline__ u32 pk_fp8(float a, float b, float c, float d) {
    int v = __builtin_amdgcn_cvt_pk_fp8_f32(a, b, 0, false);
    v = __builtin_amdgcn_cvt_pk_fp8_f32(c, d, v, true);
    return (u32)v;
}
__device__ __forceinline__ void gl_lds16(const void* g, void* l) {
    __builtin_amdgcn_global_load_lds(
        (const __attribute__((address_space(1))) u32*)g,
        (__attribute__((address_space(3))) u32*)l, 16, 0, 0);
}
#define MFMA8(A, B, C) __builtin_amdgcn_mfma_f32_32x32x16_fp8_fp8((A), (B), (C), 0, 0, 0)

// ---------------- kernel 1: row l2-norm -> fp8 fb (row-major) + fp8 fv (V^T tile images) ----
__global__ __launch_bounds__(256) void k_prep(const float* __restrict__ in,
                                              u8* __restrict__ fb, u8* __restrict__ fv) {
    __shared__ u16 t[32 * 260];
    const int tid = threadIdx.x;
    const int wave = tid >> 6, lane = tid & 63;
    const int kb = blockIdx.x, r0 = kb * 32;
    #pragma unroll
    for (int i = 0; i < 8; ++i) {
        const int rl = wave * 8 + i;
        const float4 v = *(const float4*)(in + (size_t)(r0 + rl) * DIM + lane * 4);
        float ss = v.x * v.x + v.y * v.y + v.z * v.z + v.w * v.w;
        #pragma unroll
        for (int off = 1; off < 64; off <<= 1) ss += __shfl_xor(ss, off, 64);
        const float inv = 1.0f / fmaxf(sqrtf(ss), 1e-12f);
        const float n0 = v.x * inv, n1 = v.y * inv, n2 = v.z * inv, n3 = v.w * inv;
        *(u32*)(fb + (size_t)(r0 + rl) * DIM + lane * 4) = pk_fp8(n0, n1, n2, n3);
        *(u64*)(&t[rl * 260 + lane * 4]) = pack4bf(n0, n1, n2, n3);
    }
    __syncthreads();
    #pragma unroll
    for (int i = 0; i < 4; ++i) {
        const int S = i * 256 + tid;              // 8-byte slot index 0..1023
        const int d = S >> 2;
        const int c = ((S & 3) - (d >> 2)) & 3;   // key octet
        float f[8];
        #pragma unroll
        for (int j = 0; j < 8; ++j) f[j] = bf2f(t[(8 * c + j) * 260 + d]);
        const u32 lo = pk_fp8(f[0], f[1], f[2], f[3]);
        const u32 hi = pk_fp8(f[4], f[5], f[6], f[7]);
        *(u64*)(fv + (size_t)kb * 8192 + S * 8) = ((u64)hi << 32) | lo;
    }
}

// ---------------- kernel 2: fp8 flash attention + last-arriver merge ----------------
// Main loop byte-identical to R12 (67.4us; 248/256 regs -- NO new live state
// across the loop, per the R14 register-wall lesson).
// R16: k_combine folded in via a per-qblk ticket: after a block publishes its
// Opart/lpart partial (__threadfence release = the L2 writeback the old kernel
// boundary did anyway) it atomicAdd's ticket[qblk]; the 8th arriver -- whichever
// block, any order, no spinning, no co-residency assumption (R15's cooperative
// launch never ran under graph capture) -- acquires and merges the 8 partials
// for its 128 rows: blend + final l2norm + store. Merge math is expression-
// identical to old k_combine -> bit-identical output. Removes one dispatch +
// one boundary, and merge overlaps straggler flash blocks.
__global__ __launch_bounds__(256, 2) void k_flash(
        const u8* __restrict__ fb, const u8* __restrict__ fv,
        const float* __restrict__ feats,
        u16* __restrict__ Opart, float* __restrict__ lpart,
        u32* __restrict__ ticket, float* __restrict__ out) {
    __shared__ u8 tileK[2][8192];   // key-major fp8, chunk-swizzled (16B chunks)
    __shared__ u8 tileV[2][8192];   // pre-swizzled V^T fp8 image
    __shared__ int s_last;

    const int tid = threadIdx.x;
    const int wave = tid >> 6, lane = tid & 63;
    const int c31 = lane & 31, g1 = lane >> 5;
    const int split = blockIdx.x & (NSPLIT - 1);
    const int qblk = blockIdx.x >> 3;
    const int q0 = qblk * 128 + wave * 32;
    const int key0 = split * KPS;

    // Q B-frags
    i64 qf[16];
    #pragma unroll
    for (int kc = 0; kc < 16; ++kc)
        qf[kc] = *(const i64*)(fb + (size_t)(q0 + c31) * DIM + kc * 16 + g1 * 8);

    floatx16 o[8];
    #pragma unroll
    for (int i = 0; i < 8; ++i)
        #pragma unroll
        for (int r = 0; r < 16; ++r) o[i][r] = 0.f;
    float lsum = 0.f;

    int offK[2];
    #pragma unroll
    for (int i = 0; i < 2; ++i) {
        const int S = wave * 128 + i * 64 + lane;   // 16B slot 0..511
        const int r = S >> 4, s = S & 15;
        const int c = (s & 8) | ((s ^ r) & 7);
        offK[i] = r * 256 + c * 16;
    }
    const u8* gK = fb + (size_t)key0 * DIM;
    const u8* gV = fv + (size_t)(key0 >> 5) * 8192;

    auto stage = [&](int s, int b) {
        const size_t oo = (size_t)s * 8192;
        u8* lK = &tileK[b][0] + wave * 2048;
        u8* lV = &tileV[b][0] + wave * 2048;
        #pragma unroll
        for (int i = 0; i < 2; ++i) gl_lds16(gK + oo + offK[i], lK + i * 1024);
        #pragma unroll
        for (int i = 0; i < 2; ++i)
            gl_lds16(gV + oo + wave * 2048 + i * 1024 + lane * 16, lV + i * 1024);
    };

    const int cswA = (g1 + (c31 >> 2)) & 3;          // V chunk swizzle, kc2=0
    const int cswB = (2 + g1 + (c31 >> 2)) & 3;      // kc2=1
    const int kx = (c31 & 7) << 4;                   // XOR component of K chunk swizzle

    stage(0, 0);
    for (int it = 0; it < NIT; ++it) {
        const int b = it & 1;
        __syncthreads();                   // drains DMA(it), issued one iter ago
        if (it + 1 < NIT) stage(it + 1, b ^ 1);

        const u8* tk = &tileK[b][0];
        const u8* tv = &tileV[b][0];
        const u8* bk = tk + c31 * 256 + g1 * 8;

        floatx16 s;
        #pragma unroll
        for (int r = 0; r < 16; ++r) s[r] = 0.f;

        // ---- QK group 1 (kc 0..7): 8 conflict-free kf b64 reads + vfa loads ----
        i64 kf[8], vfa[8];
        #pragma unroll
        for (int j = 0; j < 8; ++j)
            kf[j] = *(const i64*)(bk + (kx ^ (j << 4)));
        #pragma unroll
        for (int dp = 0; dp < 4; ++dp) {   // vf kc2=0, ds pairs (0,1)(2,3)(4,5)(6,7)
            const u8* ba = tv + (((dp * 2) * 32 + c31) * 4 + cswA) * 8;
            vfa[2 * dp] = *(const i64*)(ba);
            vfa[2 * dp + 1] = *(const i64*)(ba + 1024);
        }
        #pragma unroll
        for (int j = 0; j < 8; ++j) s = MFMA8(kf[j], qf[j], s);

        // ---- QK group 2 (kc 8..15) + vfb loads overlapped ----
        i64 vfb[8];
        #pragma unroll
        for (int j = 0; j < 8; ++j)
            kf[j] = *(const i64*)(bk + 128 + (kx ^ (j << 4)));
        #pragma unroll
        for (int dp = 0; dp < 4; ++dp) {   // vf kc2=1
            const u8* ba = tv + (((dp * 2) * 32 + c31) * 4 + cswB) * 8;
            vfb[2 * dp] = *(const i64*)(ba);
            vfb[2 * dp + 1] = *(const i64*)(ba + 1024);
        }
        #pragma unroll
        for (int j = 0; j < 8; ++j) s = MFMA8(kf[j], qf[8 + j], s);

        // ---- phase A: exp first half -> A0 ----
        const float e0 = __expf(s[0]), e1 = __expf(s[1]), e2 = __expf(s[2]), e3 = __expf(s[3]);
        const float e4 = __expf(s[4]), e5 = __expf(s[5]), e6 = __expf(s[6]), e7 = __expf(s[7]);
        const u32 p0 = pk_fp8(e0, e1, e2, e3);
        const u32 p1 = pk_fp8(e4, e5, e6, e7);
        const u32 x0 = (u32)__shfl_xor((int)(g1 ? p0 : p1), 32, 64);
        const i64 A0 = g1 ? (i64)(((u64)p1 << 32) | x0) : (i64)(((u64)x0 << 32) | p0);

        // ---- phase B: PV kc2=0 MFMAs interleaved with exp second half -> A1 ----
        o[0] = MFMA8(A0, vfa[0], o[0]);
        const float e8 = __expf(s[8]), e9 = __expf(s[9]);
        o[1] = MFMA8(A0, vfa[1], o[1]);
        const float e10 = __expf(s[10]), e11 = __expf(s[11]);
        o[2] = MFMA8(A0, vfa[2], o[2]);
        const float e12 = __expf(s[12]), e13 = __expf(s[13]);
        o[3] = MFMA8(A0, vfa[3], o[3]);
        const float e14 = __expf(s[14]), e15 = __expf(s[15]);
        o[4] = MFMA8(A0, vfa[4], o[4]);
        const u32 p2 = pk_fp8(e8, e9, e10, e11);
        lsum += (e0 + e1) + (e2 + e3);
        o[5] = MFMA8(A0, vfa[5], o[5]);
        const u32 p3 = pk_fp8(e12, e13, e14, e15);
        lsum += (e4 + e5) + (e6 + e7);
        o[6] = MFMA8(A0, vfa[6], o[6]);
        const u32 x1 = (u32)__shfl_xor((int)(g1 ? p2 : p3), 32, 64);
        lsum += (e8 + e9) + (e10 + e11);
        o[7] = MFMA8(A0, vfa[7], o[7]);
        const i64 A1 = g1 ? (i64)(((u64)p3 << 32) | x1) : (i64)(((u64)x1 << 32) | p2);
        lsum += (e12 + e13) + (e14 + e15);

        // ---- phase C: PV kc2=1 ----
        #pragma unroll
        for (int ds = 0; ds < 8; ++ds) o[ds] = MFMA8(A1, vfb[ds], o[ds]);
    }

    // ---- epilogue: bf16 partial O + fp32 partial l ----
    u16* ob = Opart + ((size_t)split * BN + q0) * DIM;
    #pragma unroll
    for (int ds = 0; ds < 8; ++ds) {
        #pragma unroll
        for (int r = 0; r < 16; ++r) {
            const int ql = (r & 3) + 8 * (r >> 2) + 4 * g1;
            ob[(size_t)ql * DIM + ds * 32 + c31] = f2bf(o[ds][r]);
        }
    }
    lsum += __shfl_xor(lsum, 32, 64);
    if (g1 == 0) lpart[(size_t)split * BN + q0 + c31] = lsum;

    // ---- publish partial (release), then last arriver merges this qblk ----
    __threadfence();                 // device-scope release of Opart/lpart writes
    __syncthreads();                 // all waves' writes+fences precede the ticket
    if (tid == 0) s_last = (atomicAdd(&ticket[qblk], 1u) == NSPLIT - 1);
    __syncthreads();
    if (s_last) {
        __threadfence();             // acquire: see all 8 splits' partials
        const int rowbase = qblk * 128;
        #pragma unroll 1
        for (int rr = 0; rr < 32; ++rr) {
            const int row = rowbase + wave * 32 + rr;

            float L = 0.f;
            #pragma unroll
            for (int s = 0; s < NSPLIT; ++s) L += lpart[(size_t)s * BN + row];

            float a0 = 0.f, a1 = 0.f, a2 = 0.f, a3 = 0.f;
            #pragma unroll
            for (int s = 0; s < NSPLIT; ++s) {
                const ushort4 ov = *(const ushort4*)(Opart + ((size_t)s * BN + row) * DIM + lane * 4);
                a0 += bf2f(ov.x); a1 += bf2f(ov.y); a2 += bf2f(ov.z); a3 += bf2f(ov.w);
            }
            const float invL = 1.0f / L;

            const float4 v = *(const float4*)(feats + (size_t)row * DIM + lane * 4);
            float ss = v.x * v.x + v.y * v.y + v.z * v.z + v.w * v.w;
            #pragma unroll
            for (int off = 1; off < 64; off <<= 1) ss += __shfl_xor(ss, off, 64);
            const float invf = 1.0f / fmaxf(sqrtf(ss), 1e-12f);

            const float yx = 0.8f * v.x * invf + 0.2f * a0 * invL;
            const float yy = 0.8f * v.y * invf + 0.2f * a1 * invL;
            const float yz = 0.8f * v.z * invf + 0.2f * a2 * invL;
            const float yw = 0.8f * v.w * invf + 0.2f * a3 * invL;

            float s2 = yx * yx + yy * yy + yz * yz + yw * yw;
            #pragma unroll
            for (int off = 1; off < 64; off <<= 1) s2 += __shfl_xor(s2, off, 64);
            const float invn = 1.0f / fmaxf(sqrtf(s2), 1e-12f);

            float4 ovec; ovec.x = yx * invn; ovec.y = yy * invn;
            ovec.z = yz * invn; ovec.w = yw * invn;
            *(float4*)(out + (size_t)row * DIM + lane * 4) = ovec;
        }
    }
}

// ---------------- launcher ----------------
extern "C" void kernel_launch(void* const* d_in, const int* in_sizes, int n_in,
                              void* d_out, int out_size, void* d_ws, size_t ws_size,
                              hipStream_t stream) {
    const float* feats = (const float*)d_in[0];
    float* out = (float*)d_out;
    char* ws = (char*)d_ws;

    // ws: fb fp8 2MB | fv fp8 2MB | Opart bf16 32MB | lpart fp32 256KB | ticket 256B
    u8* fb = (u8*)ws;
    u8* fv = (u8*)(ws + (size_t)BN * DIM);
    u16* Op = (u16*)(ws + (size_t)BN * DIM * 2);
    float* lp = (float*)(ws + (size_t)BN * DIM * 2 + (size_t)NSPLIT * BN * DIM * 2);
    u32* tk = (u32*)(ws + (size_t)BN * DIM * 2 + (size_t)NSPLIT * BN * DIM * 2
                        + (size_t)NSPLIT * BN * 4);

    hipMemsetAsync(tk, 0, NQB * sizeof(u32), stream);
    k_prep<<<BN / 32, 256, 0, stream>>>(feats, fb, fv);
    k_flash<<<NQB * NSPLIT, 256, 0, stream>>>(fb, fv, feats, Op, lp, tk, out);
}

// Round 6
// 160.296 us; speedup vs baseline: 1.5803x; 1.5803x over previous
//
#include <hip/hip_runtime.h>

typedef unsigned char u8;
typedef unsigned short u16;
typedef unsigned int u32;
typedef unsigned long long u64;
typedef long long i64;
typedef __attribute__((ext_vector_type(16))) float floatx16;

#define BN 8192
#define DIM 256
#define NSPLIT 8
#define KPS (BN / NSPLIT)   // 1024 keys per split
#define BKN 32              // keys per iter
#define NIT (KPS / BKN)     // 32 iters
#define NQB (BN / 128)      // 64 q-blocks

__device__ __forceinline__ u16 f2bf(float x) {
    u32 u = __builtin_bit_cast(u32, x);
    u = (u + 0x7fffu + ((u >> 16) & 1u)) >> 16;
    return (u16)u;
}
__device__ __forceinline__ float bf2f(u16 h) {
    return __builtin_bit_cast(float, (u32)h << 16);
}
__device__ __forceinline__ u64 pack4bf(float a, float b, float c, float d) {
    return (u64)f2bf(a) | ((u64)f2bf(b) << 16) | ((u64)f2bf(c) << 32) | ((u64)f2bf(d) << 48);
}
__device__ __forceinline__ u32 pk_fp8(float a, float b, float c, float d) {
    int v = __builtin_amdgcn_cvt_pk_fp8_f32(a, b, 0, false);
    v = __builtin_amdgcn_cvt_pk_fp8_f32(c, d, v, true);
    return (u32)v;
}
__device__ __forceinline__ void gl_lds16(const void* g, void* l) {
    __builtin_amdgcn_global_load_lds(
        (const __attribute__((address_space(1))) u32*)g,
        (__attribute__((address_space(3))) u32*)l, 16, 0, 0);
}
// --- per-op agent(device)-scope coherent accesses: compile to global_{load,store}
// with sc0/sc1 set -> write-through / fetch at the memory-side coherence point.
// No buffer_wbl2 / buffer_inv cache maintenance (R15b lesson: __threadfence's
// L2 writeback+invalidate per block tripled the kernel).
__device__ __forceinline__ void st_u16_ag(u16* p, u16 v) {
    __hip_atomic_store(p, v, __ATOMIC_RELAXED, __HIP_MEMORY_SCOPE_AGENT);
}
__device__ __forceinline__ void st_f32_ag(float* p, float v) {
    __hip_atomic_store(p, v, __ATOMIC_RELAXED, __HIP_MEMORY_SCOPE_AGENT);
}
__device__ __forceinline__ u64 ld_u64_ag(const u64* p) {
    return __hip_atomic_load(p, __ATOMIC_RELAXED, __HIP_MEMORY_SCOPE_AGENT);
}
__device__ __forceinline__ float ld_f32_ag(const float* p) {
    return __hip_atomic_load(p, __ATOMIC_RELAXED, __HIP_MEMORY_SCOPE_AGENT);
}
#define MFMA8(A, B, C) __builtin_amdgcn_mfma_f32_32x32x16_fp8_fp8((A), (B), (C), 0, 0, 0)

// ---------------- kernel 1: row l2-norm -> fp8 fb (row-major) + fp8 fv (V^T tile images) ----
__global__ __launch_bounds__(256) void k_prep(const float* __restrict__ in,
                                              u8* __restrict__ fb, u8* __restrict__ fv) {
    __shared__ u16 t[32 * 260];
    const int tid = threadIdx.x;
    const int wave = tid >> 6, lane = tid & 63;
    const int kb = blockIdx.x, r0 = kb * 32;
    #pragma unroll
    for (int i = 0; i < 8; ++i) {
        const int rl = wave * 8 + i;
        const float4 v = *(const float4*)(in + (size_t)(r0 + rl) * DIM + lane * 4);
        float ss = v.x * v.x + v.y * v.y + v.z * v.z + v.w * v.w;
        #pragma unroll
        for (int off = 1; off < 64; off <<= 1) ss += __shfl_xor(ss, off, 64);
        const float inv = 1.0f / fmaxf(sqrtf(ss), 1e-12f);
        const float n0 = v.x * inv, n1 = v.y * inv, n2 = v.z * inv, n3 = v.w * inv;
        *(u32*)(fb + (size_t)(r0 + rl) * DIM + lane * 4) = pk_fp8(n0, n1, n2, n3);
        *(u64*)(&t[rl * 260 + lane * 4]) = pack4bf(n0, n1, n2, n3);
    }
    __syncthreads();
    #pragma unroll
    for (int i = 0; i < 4; ++i) {
        const int S = i * 256 + tid;              // 8-byte slot index 0..1023
        const int d = S >> 2;
        const int c = ((S & 3) - (d >> 2)) & 3;   // key octet
        float f[8];
        #pragma unroll
        for (int j = 0; j < 8; ++j) f[j] = bf2f(t[(8 * c + j) * 260 + d]);
        const u32 lo = pk_fp8(f[0], f[1], f[2], f[3]);
        const u32 hi = pk_fp8(f[4], f[5], f[6], f[7]);
        *(u64*)(fv + (size_t)kb * 8192 + S * 8) = ((u64)hi << 32) | lo;
    }
}

// ---------------- kernel 2: fp8 flash attention + last-arriver merge ----------------
// Main loop byte-identical to R12 (67.4us). Fusion keeps R16's per-qblk ticket
// (removes the k_combine dispatch + boundary; merge overlaps stragglers) but
// R16b replaces the __threadfence pair (agent fence = full L2 writeback +
// invalidate per block -> 225us) with per-op sc0/sc1 coherent stores/loads:
//  * Opart/lpart published via agent-scope relaxed atomic stores (write-through
//    to the memory-side coherence point; no dirty L2 lines -> nothing to flush)
//  * release = s_waitcnt vmcnt(0) only (sc1 store ack == at coherence point)
//  * merge reads via agent-scope relaxed atomic loads (fetch from LLC; cannot
//    see stale L2). Acquire ordering via control dependency on the ticket.
__global__ __launch_bounds__(256, 2) void k_flash(
        const u8* __restrict__ fb, const u8* __restrict__ fv,
        const float* __restrict__ feats,
        u16* __restrict__ Opart, float* __restrict__ lpart,
        u32* __restrict__ ticket, float* __restrict__ out) {
    __shared__ u8 tileK[2][8192];   // key-major fp8, chunk-swizzled (16B chunks)
    __shared__ u8 tileV[2][8192];   // pre-swizzled V^T fp8 image
    __shared__ int s_last;

    const int tid = threadIdx.x;
    const int wave = tid >> 6, lane = tid & 63;
    const int c31 = lane & 31, g1 = lane >> 5;
    const int split = blockIdx.x & (NSPLIT - 1);
    const int qblk = blockIdx.x >> 3;
    const int q0 = qblk * 128 + wave * 32;
    const int key0 = split * KPS;

    // Q B-frags
    i64 qf[16];
    #pragma unroll
    for (int kc = 0; kc < 16; ++kc)
        qf[kc] = *(const i64*)(fb + (size_t)(q0 + c31) * DIM + kc * 16 + g1 * 8);

    floatx16 o[8];
    #pragma unroll
    for (int i = 0; i < 8; ++i)
        #pragma unroll
        for (int r = 0; r < 16; ++r) o[i][r] = 0.f;
    float lsum = 0.f;

    int offK[2];
    #pragma unroll
    for (int i = 0; i < 2; ++i) {
        const int S = wave * 128 + i * 64 + lane;   // 16B slot 0..511
        const int r = S >> 4, s = S & 15;
        const int c = (s & 8) | ((s ^ r) & 7);
        offK[i] = r * 256 + c * 16;
    }
    const u8* gK = fb + (size_t)key0 * DIM;
    const u8* gV = fv + (size_t)(key0 >> 5) * 8192;

    auto stage = [&](int s, int b) {
        const size_t oo = (size_t)s * 8192;
        u8* lK = &tileK[b][0] + wave * 2048;
        u8* lV = &tileV[b][0] + wave * 2048;
        #pragma unroll
        for (int i = 0; i < 2; ++i) gl_lds16(gK + oo + offK[i], lK + i * 1024);
        #pragma unroll
        for (int i = 0; i < 2; ++i)
            gl_lds16(gV + oo + wave * 2048 + i * 1024 + lane * 16, lV + i * 1024);
    };

    const int cswA = (g1 + (c31 >> 2)) & 3;          // V chunk swizzle, kc2=0
    const int cswB = (2 + g1 + (c31 >> 2)) & 3;      // kc2=1
    const int kx = (c31 & 7) << 4;                   // XOR component of K chunk swizzle

    stage(0, 0);
    for (int it = 0; it < NIT; ++it) {
        const int b = it & 1;
        __syncthreads();                   // drains DMA(it), issued one iter ago
        if (it + 1 < NIT) stage(it + 1, b ^ 1);

        const u8* tk = &tileK[b][0];
        const u8* tv = &tileV[b][0];
        const u8* bk = tk + c31 * 256 + g1 * 8;

        floatx16 s;
        #pragma unroll
        for (int r = 0; r < 16; ++r) s[r] = 0.f;

        // ---- QK group 1 (kc 0..7): 8 conflict-free kf b64 reads + vfa loads ----
        i64 kf[8], vfa[8];
        #pragma unroll
        for (int j = 0; j < 8; ++j)
            kf[j] = *(const i64*)(bk + (kx ^ (j << 4)));
        #pragma unroll
        for (int dp = 0; dp < 4; ++dp) {   // vf kc2=0, ds pairs (0,1)(2,3)(4,5)(6,7)
            const u8* ba = tv + (((dp * 2) * 32 + c31) * 4 + cswA) * 8;
            vfa[2 * dp] = *(const i64*)(ba);
            vfa[2 * dp + 1] = *(const i64*)(ba + 1024);
        }
        #pragma unroll
        for (int j = 0; j < 8; ++j) s = MFMA8(kf[j], qf[j], s);

        // ---- QK group 2 (kc 8..15) + vfb loads overlapped ----
        i64 vfb[8];
        #pragma unroll
        for (int j = 0; j < 8; ++j)
            kf[j] = *(const i64*)(bk + 128 + (kx ^ (j << 4)));
        #pragma unroll
        for (int dp = 0; dp < 4; ++dp) {   // vf kc2=1
            const u8* ba = tv + (((dp * 2) * 32 + c31) * 4 + cswB) * 8;
            vfb[2 * dp] = *(const i64*)(ba);
            vfb[2 * dp + 1] = *(const i64*)(ba + 1024);
        }
        #pragma unroll
        for (int j = 0; j < 8; ++j) s = MFMA8(kf[j], qf[8 + j], s);

        // ---- phase A: exp first half -> A0 ----
        const float e0 = __expf(s[0]), e1 = __expf(s[1]), e2 = __expf(s[2]), e3 = __expf(s[3]);
        const float e4 = __expf(s[4]), e5 = __expf(s[5]), e6 = __expf(s[6]), e7 = __expf(s[7]);
        const u32 p0 = pk_fp8(e0, e1, e2, e3);
        const u32 p1 = pk_fp8(e4, e5, e6, e7);
        const u32 x0 = (u32)__shfl_xor((int)(g1 ? p0 : p1), 32, 64);
        const i64 A0 = g1 ? (i64)(((u64)p1 << 32) | x0) : (i64)(((u64)x0 << 32) | p0);

        // ---- phase B: PV kc2=0 MFMAs interleaved with exp second half -> A1 ----
        o[0] = MFMA8(A0, vfa[0], o[0]);
        const float e8 = __expf(s[8]), e9 = __expf(s[9]);
        o[1] = MFMA8(A0, vfa[1], o[1]);
        const float e10 = __expf(s[10]), e11 = __expf(s[11]);
        o[2] = MFMA8(A0, vfa[2], o[2]);
        const float e12 = __expf(s[12]), e13 = __expf(s[13]);
        o[3] = MFMA8(A0, vfa[3], o[3]);
        const float e14 = __expf(s[14]), e15 = __expf(s[15]);
        o[4] = MFMA8(A0, vfa[4], o[4]);
        const u32 p2 = pk_fp8(e8, e9, e10, e11);
        lsum += (e0 + e1) + (e2 + e3);
        o[5] = MFMA8(A0, vfa[5], o[5]);
        const u32 p3 = pk_fp8(e12, e13, e14, e15);
        lsum += (e4 + e5) + (e6 + e7);
        o[6] = MFMA8(A0, vfa[6], o[6]);
        const u32 x1 = (u32)__shfl_xor((int)(g1 ? p2 : p3), 32, 64);
        lsum += (e8 + e9) + (e10 + e11);
        o[7] = MFMA8(A0, vfa[7], o[7]);
        const i64 A1 = g1 ? (i64)(((u64)p3 << 32) | x1) : (i64)(((u64)x1 << 32) | p2);
        lsum += (e12 + e13) + (e14 + e15);

        // ---- phase C: PV kc2=1 ----
        #pragma unroll
        for (int ds = 0; ds < 8; ++ds) o[ds] = MFMA8(A1, vfb[ds], o[ds]);
    }

    // ---- epilogue: publish bf16 partial O + fp32 partial l (agent-coherent) ----
    u16* ob = Opart + ((size_t)split * BN + q0) * DIM;
    #pragma unroll
    for (int ds = 0; ds < 8; ++ds) {
        #pragma unroll
        for (int r = 0; r < 16; ++r) {
            const int ql = (r & 3) + 8 * (r >> 2) + 4 * g1;
            st_u16_ag(&ob[(size_t)ql * DIM + ds * 32 + c31], f2bf(o[ds][r]));
        }
    }
    lsum += __shfl_xor(lsum, 32, 64);
    if (g1 == 0) st_f32_ag(&lpart[(size_t)split * BN + q0 + c31], lsum);

    // ---- release: drain sc1 stores (ack == at coherence point), then ticket ----
    asm volatile("s_waitcnt vmcnt(0)" ::: "memory");
    __syncthreads();                 // all waves drained before the ticket bump
    if (tid == 0) s_last = (atomicAdd(&ticket[qblk], 1u) == NSPLIT - 1);
    __syncthreads();
    if (s_last) {
        // acquire via control dependency: ticket==8 -> all producers' sc1
        // stores already at the coherence point; sc1 loads fetch from there.
        const int rowbase = qblk * 128;
        #pragma unroll 1
        for (int rr = 0; rr < 32; ++rr) {
            const int row = rowbase + wave * 32 + rr;

            float L = 0.f;
            #pragma unroll
            for (int s = 0; s < NSPLIT; ++s) L += ld_f32_ag(&lpart[(size_t)s * BN + row]);

            float a0 = 0.f, a1 = 0.f, a2 = 0.f, a3 = 0.f;
            #pragma unroll
            for (int s = 0; s < NSPLIT; ++s) {
                const u64 w = ld_u64_ag((const u64*)(Opart + ((size_t)s * BN + row) * DIM + lane * 4));
                a0 += bf2f((u16)w);         a1 += bf2f((u16)(w >> 16));
                a2 += bf2f((u16)(w >> 32)); a3 += bf2f((u16)(w >> 48));
            }
            const float invL = 1.0f / L;

            const float4 v = *(const float4*)(feats + (size_t)row * DIM + lane * 4);
            float ss = v.x * v.x + v.y * v.y + v.z * v.z + v.w * v.w;
            #pragma unroll
            for (int off = 1; off < 64; off <<= 1) ss += __shfl_xor(ss, off, 64);
            const float invf = 1.0f / fmaxf(sqrtf(ss), 1e-12f);

            const float yx = 0.8f * v.x * invf + 0.2f * a0 * invL;
            const float yy = 0.8f * v.y * invf + 0.2f * a1 * invL;
            const float yz = 0.8f * v.z * invf + 0.2f * a2 * invL;
            const float yw = 0.8f * v.w * invf + 0.2f * a3 * invL;

            float s2 = yx * yx + yy * yy + yz * yz + yw * yw;
            #pragma unroll
            for (int off = 1; off < 64; off <<= 1) s2 += __shfl_xor(s2, off, 64);
            const float invn = 1.0f / fmaxf(sqrtf(s2), 1e-12f);

            float4 ovec; ovec.x = yx * invn; ovec.y = yy * invn;
            ovec.z = yz * invn; ovec.w = yw * invn;
            *(float4*)(out + (size_t)row * DIM + lane * 4) = ovec;
        }
    }
}

// ---------------- launcher ----------------
extern "C" void kernel_launch(void* const* d_in, const int* in_sizes, int n_in,
                              void* d_out, int out_size, void* d_ws, size_t ws_size,
                              hipStream_t stream) {
    const float* feats = (const float*)d_in[0];
    float* out = (float*)d_out;
    char* ws = (char*)d_ws;

    // ws: fb fp8 2MB | fv fp8 2MB | Opart bf16 32MB | lpart fp32 256KB | ticket 256B
    u8* fb = (u8*)ws;
    u8* fv = (u8*)(ws + (size_t)BN * DIM);
    u16* Op = (u16*)(ws + (size_t)BN * DIM * 2);
    float* lp = (float*)(ws + (size_t)BN * DIM * 2 + (size_t)NSPLIT * BN * DIM * 2);
    u32* tk = (u32*)(ws + (size_t)BN * DIM * 2 + (size_t)NSPLIT * BN * DIM * 2
                        + (size_t)NSPLIT * BN * 4);

    hipMemsetAsync(tk, 0, NQB * sizeof(u32), stream);
    k_prep<<<BN / 32, 256, 0, stream>>>(feats, fb, fv);
    k_flash<<<NQB * NSPLIT, 256, 0, stream>>>(fb, fv, feats, Op, lp, tk, out);
}

// Round 8
// 130.060 us; speedup vs baseline: 1.9477x; 1.2325x over previous
//
#include <hip/hip_runtime.h>

typedef unsigned char u8;
typedef unsigned short u16;
typedef unsigned int u32;
typedef unsigned long long u64;
typedef long long i64;
typedef __attribute__((ext_vector_type(16))) float floatx16;

#define BN 8192
#define DIM 256
#define NSPLIT 8
#define KPS (BN / NSPLIT)   // 1024 keys per split
#define BKN 64              // keys per barrier period (2 x 32-key halves)
#define NIT (KPS / BKN)     // 16 iters

__device__ __forceinline__ u16 f2bf(float x) {
    u32 u = __builtin_bit_cast(u32, x);
    u = (u + 0x7fffu + ((u >> 16) & 1u)) >> 16;
    return (u16)u;
}
__device__ __forceinline__ float bf2f(u16 h) {
    return __builtin_bit_cast(float, (u32)h << 16);
}
__device__ __forceinline__ u64 pack4bf(float a, float b, float c, float d) {
    return (u64)f2bf(a) | ((u64)f2bf(b) << 16) | ((u64)f2bf(c) << 32) | ((u64)f2bf(d) << 48);
}
__device__ __forceinline__ u32 pk_fp8(float a, float b, float c, float d) {
    int v = __builtin_amdgcn_cvt_pk_fp8_f32(a, b, 0, false);
    v = __builtin_amdgcn_cvt_pk_fp8_f32(c, d, v, true);
    return (u32)v;
}
__device__ __forceinline__ void gl_lds16(const void* g, void* l) {
    __builtin_amdgcn_global_load_lds(
        (const __attribute__((address_space(1))) u32*)g,
        (__attribute__((address_space(3))) u32*)l, 16, 0, 0);
}
#define MFMA8(A, B, C) __builtin_amdgcn_mfma_f32_32x32x16_fp8_fp8((A), (B), (C), 0, 0, 0)

// ---------------- kernel 1: row l2-norm -> fp8 fb (row-major) + fp8 fv (V^T tile images) ----
__global__ __launch_bounds__(256) void k_prep(const float* __restrict__ in,
                                              u8* __restrict__ fb, u8* __restrict__ fv) {
    __shared__ u16 t[32 * 260];
    const int tid = threadIdx.x;
    const int wave = tid >> 6, lane = tid & 63;
    const int kb = blockIdx.x, r0 = kb * 32;
    #pragma unroll
    for (int i = 0; i < 8; ++i) {
        const int rl = wave * 8 + i;
        const float4 v = *(const float4*)(in + (size_t)(r0 + rl) * DIM + lane * 4);
        float ss = v.x * v.x + v.y * v.y + v.z * v.z + v.w * v.w;
        #pragma unroll
        for (int off = 1; off < 64; off <<= 1) ss += __shfl_xor(ss, off, 64);
        const float inv = 1.0f / fmaxf(sqrtf(ss), 1e-12f);
        const float n0 = v.x * inv, n1 = v.y * inv, n2 = v.z * inv, n3 = v.w * inv;
        *(u32*)(fb + (size_t)(r0 + rl) * DIM + lane * 4) = pk_fp8(n0, n1, n2, n3);
        *(u64*)(&t[rl * 260 + lane * 4]) = pack4bf(n0, n1, n2, n3);
    }
    __syncthreads();
    #pragma unroll
    for (int i = 0; i < 4; ++i) {
        const int S = i * 256 + tid;              // 8-byte slot index 0..1023
        const int d = S >> 2;
        const int c = ((S & 3) - (d >> 2)) & 3;   // key octet
        float f[8];
        #pragma unroll
        for (int j = 0; j < 8; ++j) f[j] = bf2f(t[(8 * c + j) * 260 + d]);
        const u32 lo = pk_fp8(f[0], f[1], f[2], f[3]);
        const u32 hi = pk_fp8(f[4], f[5], f[6], f[7]);
        *(u64*)(fv + (size_t)kb * 8192 + S * 8) = ((u64)hi << 32) | lo;
    }
}

// ---------------- kernel 2: fp8 flash attention, pipe-interleaved ----------------
// R17 resubmit (R7 bench was an infra failure; kernel never ran).
// On the proven R12/67.4us base; fused-merge line closed after R16b's
// net -30us vs 3-kernel:
//  * De-phase the 2 co-resident blocks: both run identical code launched
//    simultaneously -> VALU/MFMA phases align and the matrix pipe idles
//    (MfmaUtil 39% while no pipe is saturated = phase-lock signature).
//    Odd-split blocks s_sleep ~1000cyc (half an iteration) once -> block A's
//    MFMA clusters overlay block B's exp/VALU for the whole kernel.
//  * BKN 32->64, two SEQUENTIAL 32-key halves per barrier (R14's verified
//    staging, MINUS the kf2 prefetch that spilled): halves barrier seams,
//    zero new live state (kf/vfa/vfb dead between halves -> reused).
//  * setprio(1) around MFMA clusters (pays in the de-phased regime).
__global__ __launch_bounds__(256, 2) void k_flash(
        const u8* __restrict__ fb, const u8* __restrict__ fv,
        u16* __restrict__ Opart, float* __restrict__ lpart) {
    __shared__ u8 tileK[2][16384];  // key-major fp8, chunk-swizzled, 2x32-key halves
    __shared__ u8 tileV[2][16384];  // pre-swizzled V^T fp8 images, 2x8KB halves

    const int tid = threadIdx.x;
    const int wave = tid >> 6, lane = tid & 63;
    const int c31 = lane & 31, g1 = lane >> 5;
    const int split = blockIdx.x & (NSPLIT - 1);
    const int qblk = blockIdx.x >> 3;
    const int q0 = qblk * 128 + wave * 32;
    const int key0 = split * KPS;

    // Q B-frags
    i64 qf[16];
    #pragma unroll
    for (int kc = 0; kc < 16; ++kc)
        qf[kc] = *(const i64*)(fb + (size_t)(q0 + c31) * DIM + kc * 16 + g1 * 8);

    floatx16 o[8];
    #pragma unroll
    for (int i = 0; i < 8; ++i)
        #pragma unroll
        for (int r = 0; r < 16; ++r) o[i][r] = 0.f;
    float lsum = 0.f;

    int offK[4];
    #pragma unroll
    for (int i = 0; i < 4; ++i) {
        const int S = wave * 256 + i * 64 + lane;   // 16B slot 0..1023 (64 key rows)
        const int r = S >> 4, s = S & 15;
        const int c = (s & 8) | ((s ^ r) & 7);
        offK[i] = r * 256 + c * 16;
    }
    const u8* gK = fb + (size_t)key0 * DIM;
    const u8* gV = fv + (size_t)(key0 >> 5) * 8192;

    auto stage = [&](int s, int b) {
        const size_t oo = (size_t)s * 16384;
        u8* lK = &tileK[b][0];
        u8* lV = &tileV[b][0] + wave * 4096;
        #pragma unroll
        for (int i = 0; i < 4; ++i)
            gl_lds16(gK + oo + offK[i], lK + wave * 4096 + i * 1024);
        #pragma unroll
        for (int i = 0; i < 4; ++i)
            gl_lds16(gV + oo + wave * 4096 + i * 1024 + lane * 16, lV + i * 1024);
    };

    const int cswA = (g1 + (c31 >> 2)) & 3;          // V chunk swizzle, kc2=0
    const int cswB = (2 + g1 + (c31 >> 2)) & 3;      // kc2=1
    const int kx = (c31 & 7) << 4;                   // XOR component of K chunk swizzle

    stage(0, 0);
    // de-phase: odd splits start ~half an iteration late (s_sleep 2x512 clk)
    if (split & 1) { __builtin_amdgcn_s_sleep(8); __builtin_amdgcn_s_sleep(8); }

    for (int it = 0; it < NIT; ++it) {
        const int b = it & 1;
        __syncthreads();                   // drains DMA(it), issued one iter ago
        if (it + 1 < NIT) stage(it + 1, b ^ 1);

        const u8* tk = &tileK[b][0];
        #pragma unroll
        for (int h = 0; h < 2; ++h) {
            const u8* bk = tk + h * 8192 + c31 * 256 + g1 * 8;
            const u8* tv = &tileV[b][0] + h * 8192;

            floatx16 s;
            #pragma unroll
            for (int r = 0; r < 16; ++r) s[r] = 0.f;

            // ---- QK group 1 (kc 0..7): conflict-free kf b64 reads + vfa loads ----
            i64 kf[8], vfa[8], vfb[8];
            #pragma unroll
            for (int j = 0; j < 8; ++j)
                kf[j] = *(const i64*)(bk + (kx ^ (j << 4)));
            #pragma unroll
            for (int dp = 0; dp < 4; ++dp) {   // vf kc2=0, ds pairs
                const u8* ba = tv + (((dp * 2) * 32 + c31) * 4 + cswA) * 8;
                vfa[2 * dp] = *(const i64*)(ba);
                vfa[2 * dp + 1] = *(const i64*)(ba + 1024);
            }
            __builtin_amdgcn_s_setprio(1);
            #pragma unroll
            for (int j = 0; j < 8; ++j) s = MFMA8(kf[j], qf[j], s);
            __builtin_amdgcn_s_setprio(0);

            // ---- QK group 2 (kc 8..15) + vfb loads overlapped ----
            #pragma unroll
            for (int j = 0; j < 8; ++j)
                kf[j] = *(const i64*)(bk + 128 + (kx ^ (j << 4)));
            #pragma unroll
            for (int dp = 0; dp < 4; ++dp) {   // vf kc2=1
                const u8* ba = tv + (((dp * 2) * 32 + c31) * 4 + cswB) * 8;
                vfb[2 * dp] = *(const i64*)(ba);
                vfb[2 * dp + 1] = *(const i64*)(ba + 1024);
            }
            __builtin_amdgcn_s_setprio(1);
            #pragma unroll
            for (int j = 0; j < 8; ++j) s = MFMA8(kf[j], qf[8 + j], s);
            __builtin_amdgcn_s_setprio(0);

            // ---- phase A: exp first half -> A0 ----
            const float e0 = __expf(s[0]), e1 = __expf(s[1]), e2 = __expf(s[2]), e3 = __expf(s[3]);
            const float e4 = __expf(s[4]), e5 = __expf(s[5]), e6 = __expf(s[6]), e7 = __expf(s[7]);
            const u32 p0 = pk_fp8(e0, e1, e2, e3);
            const u32 p1 = pk_fp8(e4, e5, e6, e7);
            const u32 x0 = (u32)__shfl_xor((int)(g1 ? p0 : p1), 32, 64);
            const i64 A0 = g1 ? (i64)(((u64)p1 << 32) | x0) : (i64)(((u64)x0 << 32) | p0);

            // ---- phase B: PV kc2=0 MFMAs interleaved with exp second half -> A1 ----
            o[0] = MFMA8(A0, vfa[0], o[0]);
            const float e8 = __expf(s[8]), e9 = __expf(s[9]);
            o[1] = MFMA8(A0, vfa[1], o[1]);
            const float e10 = __expf(s[10]), e11 = __expf(s[11]);
            o[2] = MFMA8(A0, vfa[2], o[2]);
            const float e12 = __expf(s[12]), e13 = __expf(s[13]);
            o[3] = MFMA8(A0, vfa[3], o[3]);
            const float e14 = __expf(s[14]), e15 = __expf(s[15]);
            o[4] = MFMA8(A0, vfa[4], o[4]);
            const u32 p2 = pk_fp8(e8, e9, e10, e11);
            lsum += (e0 + e1) + (e2 + e3);
            o[5] = MFMA8(A0, vfa[5], o[5]);
            const u32 p3 = pk_fp8(e12, e13, e14, e15);
            lsum += (e4 + e5) + (e6 + e7);
            o[6] = MFMA8(A0, vfa[6], o[6]);
            const u32 x1 = (u32)__shfl_xor((int)(g1 ? p2 : p3), 32, 64);
            lsum += (e8 + e9) + (e10 + e11);
            o[7] = MFMA8(A0, vfa[7], o[7]);
            const i64 A1 = g1 ? (i64)(((u64)p3 << 32) | x1) : (i64)(((u64)x1 << 32) | p2);
            lsum += (e12 + e13) + (e14 + e15);

            // ---- phase C: PV kc2=1 ----
            __builtin_amdgcn_s_setprio(1);
            #pragma unroll
            for (int ds = 0; ds < 8; ++ds) o[ds] = MFMA8(A1, vfb[ds], o[ds]);
            __builtin_amdgcn_s_setprio(0);
        }
    }

    // ---- epilogue: bf16 partial O + fp32 partial l ----
    u16* ob = Opart + ((size_t)split * BN + q0) * DIM;
    #pragma unroll
    for (int ds = 0; ds < 8; ++ds) {
        #pragma unroll
        for (int r = 0; r < 16; ++r) {
            const int ql = (r & 3) + 8 * (r >> 2) + 4 * g1;
            ob[(size_t)ql * DIM + ds * 32 + c31] = f2bf(o[ds][r]);
        }
    }
    lsum += __shfl_xor(lsum, 32, 64);
    if (g1 == 0) lpart[(size_t)split * BN + q0 + c31] = lsum;
}

// ---------------- kernel 3: merge splits, blend, final l2-normalize ----------------
__global__ __launch_bounds__(256) void k_combine(
        const float* __restrict__ feats, const u16* __restrict__ Opart,
        const float* __restrict__ lpart, float* __restrict__ out) {
    const int row = blockIdx.x * 4 + (threadIdx.x >> 6);
    const int lane = threadIdx.x & 63;

    float L = 0.f;
    #pragma unroll
    for (int s = 0; s < NSPLIT; ++s) L += lpart[(size_t)s * BN + row];

    float a0 = 0.f, a1 = 0.f, a2 = 0.f, a3 = 0.f;
    #pragma unroll
    for (int s = 0; s < NSPLIT; ++s) {
        const ushort4 o = *(const ushort4*)(Opart + ((size_t)s * BN + row) * DIM + lane * 4);
        a0 += bf2f(o.x); a1 += bf2f(o.y); a2 += bf2f(o.z); a3 += bf2f(o.w);
    }
    const float invL = 1.0f / L;

    const float4 v = *(const float4*)(feats + (size_t)row * DIM + lane * 4);
    float ss = v.x * v.x + v.y * v.y + v.z * v.z + v.w * v.w;
    #pragma unroll
    for (int off = 1; off < 64; off <<= 1) ss += __shfl_xor(ss, off, 64);
    const float invf = 1.0f / fmaxf(sqrtf(ss), 1e-12f);

    const float yx = 0.8f * v.x * invf + 0.2f * a0 * invL;
    const float yy = 0.8f * v.y * invf + 0.2f * a1 * invL;
    const float yz = 0.8f * v.z * invf + 0.2f * a2 * invL;
    const float yw = 0.8f * v.w * invf + 0.2f * a3 * invL;

    float s2 = yx * yx + yy * yy + yz * yz + yw * yw;
    #pragma unroll
    for (int off = 1; off < 64; off <<= 1) s2 += __shfl_xor(s2, off, 64);
    const float invn = 1.0f / fmaxf(sqrtf(s2), 1e-12f);

    float4 o; o.x = yx * invn; o.y = yy * invn; o.z = yz * invn; o.w = yw * invn;
    *(float4*)(out + (size_t)row * DIM + lane * 4) = o;
}

// ---------------- launcher ----------------
extern "C" void kernel_launch(void* const* d_in, const int* in_sizes, int n_in,
                              void* d_out, int out_size, void* d_ws, size_t ws_size,
                              hipStream_t stream) {
    const float* feats = (const float*)d_in[0];
    float* out = (float*)d_out;
    char* ws = (char*)d_ws;

    // ws: fb fp8 2MB | fv fp8 2MB | Opart bf16 32MB | lpart fp32 256KB
    u8* fb = (u8*)ws;
    u8* fv = (u8*)(ws + (size_t)BN * DIM);
    u16* Op = (u16*)(ws + (size_t)BN * DIM * 2);
    float* lp = (float*)(ws + (size_t)BN * DIM * 2 + (size_t)NSPLIT * BN * DIM * 2);

    k_prep<<<BN / 32, 256, 0, stream>>>(feats, fb, fv);
    k_flash<<<(BN / 128) * NSPLIT, 256, 0, stream>>>(fb, fv, Op, lp);
    k_combine<<<BN / 4, 256, 0, stream>>>(feats, Op, lp, out);
}

// Round 9
// 119.948 us; speedup vs baseline: 2.1119x; 1.0843x over previous
//
#include <hip/hip_runtime.h>

typedef unsigned char u8;
typedef unsigned short u16;
typedef unsigned int u32;
typedef unsigned long long u64;
typedef long long i64;
typedef __attribute__((ext_vector_type(16))) float floatx16;
typedef __attribute__((ext_vector_type(4))) int intx4;
typedef __attribute__((ext_vector_type(8))) int intx8;

#define BN 8192
#define DIM 256
#define NSPLIT 8
#define KPS (BN / NSPLIT)   // 1024 keys per split
#define BKN 32              // keys per iter
#define NIT (KPS / BKN)     // 32 iters

__device__ __forceinline__ u16 f2bf(float x) {
    u32 u = __builtin_bit_cast(u32, x);
    u = (u + 0x7fffu + ((u >> 16) & 1u)) >> 16;
    return (u16)u;
}
__device__ __forceinline__ float bf2f(u16 h) {
    return __builtin_bit_cast(float, (u32)h << 16);
}
__device__ __forceinline__ u64 pack4bf(float a, float b, float c, float d) {
    return (u64)f2bf(a) | ((u64)f2bf(b) << 16) | ((u64)f2bf(c) << 32) | ((u64)f2bf(d) << 48);
}
__device__ __forceinline__ u32 pk_fp8(float a, float b, float c, float d) {
    int v = __builtin_amdgcn_cvt_pk_fp8_f32(a, b, 0, false);
    v = __builtin_amdgcn_cvt_pk_fp8_f32(c, d, v, true);
    return (u32)v;
}
__device__ __forceinline__ void gl_lds16(const void* g, void* l) {
    __builtin_amdgcn_global_load_lds(
        (const __attribute__((address_space(1))) u32*)g,
        (__attribute__((address_space(3))) u32*)l, 16, 0, 0);
}
#define MFMA8(A, B, C) __builtin_amdgcn_mfma_f32_32x32x16_fp8_fp8((A), (B), (C), 0, 0, 0)
// MX-scaled fp8 MFMA, K=64, unit scales (e8m0 0x7F = 2^0). Runs at the MX rate
// (4686 TF ubench = 2.13x the non-scaled fp8/bf16 rate).
#define MFMA64S(A, B, C) __builtin_amdgcn_mfma_scale_f32_32x32x64_f8f6f4( \
        (A), (B), (C), 0, 0, 0, (int)0x7f7f7f7f, 0, (int)0x7f7f7f7f)

// ---------------- kernel 1: row l2-norm -> fp8 fb (row-major) + fp8 fv (V^T tile images) ----
__global__ __launch_bounds__(256) void k_prep(const float* __restrict__ in,
                                              u8* __restrict__ fb, u8* __restrict__ fv) {
    __shared__ u16 t[32 * 260];
    const int tid = threadIdx.x;
    const int wave = tid >> 6, lane = tid & 63;
    const int kb = blockIdx.x, r0 = kb * 32;
    #pragma unroll
    for (int i = 0; i < 8; ++i) {
        const int rl = wave * 8 + i;
        const float4 v = *(const float4*)(in + (size_t)(r0 + rl) * DIM + lane * 4);
        float ss = v.x * v.x + v.y * v.y + v.z * v.z + v.w * v.w;
        #pragma unroll
        for (int off = 1; off < 64; off <<= 1) ss += __shfl_xor(ss, off, 64);
        const float inv = 1.0f / fmaxf(sqrtf(ss), 1e-12f);
        const float n0 = v.x * inv, n1 = v.y * inv, n2 = v.z * inv, n3 = v.w * inv;
        *(u32*)(fb + (size_t)(r0 + rl) * DIM + lane * 4) = pk_fp8(n0, n1, n2, n3);
        *(u64*)(&t[rl * 260 + lane * 4]) = pack4bf(n0, n1, n2, n3);
    }
    __syncthreads();
    #pragma unroll
    for (int i = 0; i < 4; ++i) {
        const int S = i * 256 + tid;              // 8-byte slot index 0..1023
        const int d = S >> 2;
        const int c = ((S & 3) - (d >> 2)) & 3;   // key octet
        float f[8];
        #pragma unroll
        for (int j = 0; j < 8; ++j) f[j] = bf2f(t[(8 * c + j) * 260 + d]);
        const u32 lo = pk_fp8(f[0], f[1], f[2], f[3]);
        const u32 hi = pk_fp8(f[4], f[5], f[6], f[7]);
        *(u64*)(fv + (size_t)kb * 8192 + S * 8) = ((u64)hi << 32) | lo;
    }
}

// ---------------- kernel 2: fp8 flash attention, pipe-interleaved ----------------
// R18 (single variable on the R12/67.4us base; R8 proved every SCHEDULE
// perturbation lands at 67.4-67.5 -> attack the per-iter MFMA invariant):
//  * QK via mfma_scale_f32_32x32x64_f8f6f4 with unit scales: 4 MFMAs/iter
//    instead of 16 chained 32x32x16 -> pipe occupancy 589->275 cyc/iter/wave,
//    serial dep chain 16->4 deep. Non-scaled fp8 runs at bf16 rate; MX-scaled
//    is the only path to the fp8 rate (2.13x).
//  * A/B fragment layout for 32x32x64: row=lane&31, k=(lane>>5)*32+byte
//    (natural extrapolation of the verified 32x32x16 mapping). C/D layout is
//    shape-determined (m128) -> s layout, exp/pack, PV, epilogue unchanged.
//  * K-frags: 2 x ds_read_b128 per 64-dim k-group from the SAME swizzled
//    tileK (chunk cw lives at slot (cw&8)|((cw^row)&7); cw even -> cw+1 at
//    slot^1). 2 lanes/bank-pair = conflict-free.
//  * PV stays K=16 (K=64 PV needs cross-half P shuffles that eat the gain).
__global__ __launch_bounds__(256, 2) void k_flash(
        const u8* __restrict__ fb, const u8* __restrict__ fv,
        u16* __restrict__ Opart, float* __restrict__ lpart) {
    __shared__ u8 tileK[2][8192];   // key-major fp8, chunk-swizzled (16B chunks)
    __shared__ u8 tileV[2][8192];   // pre-swizzled V^T fp8 image

    const int tid = threadIdx.x;
    const int wave = tid >> 6, lane = tid & 63;
    const int c31 = lane & 31, g1 = lane >> 5;
    const int split = blockIdx.x & (NSPLIT - 1);
    const int qblk = blockIdx.x >> 3;
    const int q0 = qblk * 128 + wave * 32;
    const int key0 = split * KPS;

    // Q B-frags for K=64 MFMA: lane (c31,g1) holds q row q0+c31,
    // dims g*64 + g1*32 .. +32  (4 groups x 8 VGPRs = 32 VGPRs, same as before)
    intx8 qf[4];
    #pragma unroll
    for (int g = 0; g < 4; ++g) {
        const u8* qb = fb + (size_t)(q0 + c31) * DIM + g * 64 + g1 * 32;
        const intx4 lo = *(const intx4*)(qb);
        const intx4 hi = *(const intx4*)(qb + 16);
        qf[g] = __builtin_shufflevector(lo, hi, 0, 1, 2, 3, 4, 5, 6, 7);
    }

    floatx16 o[8];
    #pragma unroll
    for (int i = 0; i < 8; ++i)
        #pragma unroll
        for (int r = 0; r < 16; ++r) o[i][r] = 0.f;
    float lsum = 0.f;

    int offK[2];
    #pragma unroll
    for (int i = 0; i < 2; ++i) {
        const int S = wave * 128 + i * 64 + lane;   // 16B slot 0..511
        const int r = S >> 4, s = S & 15;
        const int c = (s & 8) | ((s ^ r) & 7);
        offK[i] = r * 256 + c * 16;
    }
    const u8* gK = fb + (size_t)key0 * DIM;
    const u8* gV = fv + (size_t)(key0 >> 5) * 8192;

    auto stage = [&](int s, int b) {
        const size_t oo = (size_t)s * 8192;
        u8* lK = &tileK[b][0] + wave * 2048;
        u8* lV = &tileV[b][0] + wave * 2048;
        #pragma unroll
        for (int i = 0; i < 2; ++i) gl_lds16(gK + oo + offK[i], lK + i * 1024);
        #pragma unroll
        for (int i = 0; i < 2; ++i)
            gl_lds16(gV + oo + wave * 2048 + i * 1024 + lane * 16, lV + i * 1024);
    };

    const int cswA = (g1 + (c31 >> 2)) & 3;          // V chunk swizzle, kc2=0
    const int cswB = (2 + g1 + (c31 >> 2)) & 3;      // kc2=1

    stage(0, 0);
    for (int it = 0; it < NIT; ++it) {
        const int b = it & 1;
        __syncthreads();                   // drains DMA(it), issued one iter ago
        if (it + 1 < NIT) stage(it + 1, b ^ 1);

        const u8* tk = &tileK[b][0];
        const u8* tv = &tileV[b][0];
        const u8* bk = tk + c31 * 256;

        // K A-frag loader for k-group g: lane (c31,g1) needs key row c31,
        // dims g*64 + g1*32 .. +32 = global chunks cw, cw+1 (cw = 4g + 2*g1).
        // Chunk cw lives at swizzled slot (cw&8)|((cw^c31)&7); cw+1 at slot^1.
        auto ldk = [&](int g) -> intx8 {
            const int cw = g * 4 + g1 * 2;
            const int sl = (cw & 8) | ((cw ^ c31) & 7);
            const intx4 lo = *(const intx4*)(bk + sl * 16);
            const intx4 hi = *(const intx4*)(bk + (sl ^ 1) * 16);
            return __builtin_shufflevector(lo, hi, 0, 1, 2, 3, 4, 5, 6, 7);
        };

        floatx16 s;
        #pragma unroll
        for (int r = 0; r < 16; ++r) s[r] = 0.f;

        // ---- QK: 4 x K=64 scaled MFMAs, k-frag loads + vf loads overlapped ----
        i64 vfa[8], vfb[8];
        intx8 ka0 = ldk(0);
        intx8 ka1 = ldk(1);
        #pragma unroll
        for (int dp = 0; dp < 4; ++dp) {   // vf kc2=0, ds pairs (0,1)(2,3)(4,5)(6,7)
            const u8* ba = tv + (((dp * 2) * 32 + c31) * 4 + cswA) * 8;
            vfa[2 * dp] = *(const i64*)(ba);
            vfa[2 * dp + 1] = *(const i64*)(ba + 1024);
        }
        s = MFMA64S(ka0, qf[0], s);
        ka0 = ldk(2);
        s = MFMA64S(ka1, qf[1], s);
        ka1 = ldk(3);
        #pragma unroll
        for (int dp = 0; dp < 4; ++dp) {   // vf kc2=1
            const u8* ba = tv + (((dp * 2) * 32 + c31) * 4 + cswB) * 8;
            vfb[2 * dp] = *(const i64*)(ba);
            vfb[2 * dp + 1] = *(const i64*)(ba + 1024);
        }
        s = MFMA64S(ka0, qf[2], s);
        s = MFMA64S(ka1, qf[3], s);

        // ---- phase A: exp first half -> A0 ----
        const float e0 = __expf(s[0]), e1 = __expf(s[1]), e2 = __expf(s[2]), e3 = __expf(s[3]);
        const float e4 = __expf(s[4]), e5 = __expf(s[5]), e6 = __expf(s[6]), e7 = __expf(s[7]);
        const u32 p0 = pk_fp8(e0, e1, e2, e3);
        const u32 p1 = pk_fp8(e4, e5, e6, e7);
        const u32 x0 = (u32)__shfl_xor((int)(g1 ? p0 : p1), 32, 64);
        const i64 A0 = g1 ? (i64)(((u64)p1 << 32) | x0) : (i64)(((u64)x0 << 32) | p0);

        // ---- phase B: PV kc2=0 MFMAs interleaved with exp second half -> A1 ----
        o[0] = MFMA8(A0, vfa[0], o[0]);
        const float e8 = __expf(s[8]), e9 = __expf(s[9]);
        o[1] = MFMA8(A0, vfa[1], o[1]);
        const float e10 = __expf(s[10]), e11 = __expf(s[11]);
        o[2] = MFMA8(A0, vfa[2], o[2]);
        const float e12 = __expf(s[12]), e13 = __expf(s[13]);
        o[3] = MFMA8(A0, vfa[3], o[3]);
        const float e14 = __expf(s[14]), e15 = __expf(s[15]);
        o[4] = MFMA8(A0, vfa[4], o[4]);
        const u32 p2 = pk_fp8(e8, e9, e10, e11);
        lsum += (e0 + e1) + (e2 + e3);
        o[5] = MFMA8(A0, vfa[5], o[5]);
        const u32 p3 = pk_fp8(e12, e13, e14, e15);
        lsum += (e4 + e5) + (e6 + e7);
        o[6] = MFMA8(A0, vfa[6], o[6]);
        const u32 x1 = (u32)__shfl_xor((int)(g1 ? p2 : p3), 32, 64);
        lsum += (e8 + e9) + (e10 + e11);
        o[7] = MFMA8(A0, vfa[7], o[7]);
        const i64 A1 = g1 ? (i64)(((u64)p3 << 32) | x1) : (i64)(((u64)x1 << 32) | p2);
        lsum += (e12 + e13) + (e14 + e15);

        // ---- phase C: PV kc2=1 ----
        #pragma unroll
        for (int ds = 0; ds < 8; ++ds) o[ds] = MFMA8(A1, vfb[ds], o[ds]);
    }

    // ---- epilogue: bf16 partial O + fp32 partial l ----
    u16* ob = Opart + ((size_t)split * BN + q0) * DIM;
    #pragma unroll
    for (int ds = 0; ds < 8; ++ds) {
        #pragma unroll
        for (int r = 0; r < 16; ++r) {
            const int ql = (r & 3) + 8 * (r >> 2) + 4 * g1;
            ob[(size_t)ql * DIM + ds * 32 + c31] = f2bf(o[ds][r]);
        }
    }
    lsum += __shfl_xor(lsum, 32, 64);
    if (g1 == 0) lpart[(size_t)split * BN + q0 + c31] = lsum;
}

// ---------------- kernel 3: merge splits, blend, final l2-normalize ----------------
__global__ __launch_bounds__(256) void k_combine(
        const float* __restrict__ feats, const u16* __restrict__ Opart,
        const float* __restrict__ lpart, float* __restrict__ out) {
    const int row = blockIdx.x * 4 + (threadIdx.x >> 6);
    const int lane = threadIdx.x & 63;

    float L = 0.f;
    #pragma unroll
    for (int s = 0; s < NSPLIT; ++s) L += lpart[(size_t)s * BN + row];

    float a0 = 0.f, a1 = 0.f, a2 = 0.f, a3 = 0.f;
    #pragma unroll
    for (int s = 0; s < NSPLIT; ++s) {
        const ushort4 o = *(const ushort4*)(Opart + ((size_t)s * BN + row) * DIM + lane * 4);
        a0 += bf2f(o.x); a1 += bf2f(o.y); a2 += bf2f(o.z); a3 += bf2f(o.w);
    }
    const float invL = 1.0f / L;

    const float4 v = *(const float4*)(feats + (size_t)row * DIM + lane * 4);
    float ss = v.x * v.x + v.y * v.y + v.z * v.z + v.w * v.w;
    #pragma unroll
    for (int off = 1; off < 64; off <<= 1) ss += __shfl_xor(ss, off, 64);
    const float invf = 1.0f / fmaxf(sqrtf(ss), 1e-12f);

    const float yx = 0.8f * v.x * invf + 0.2f * a0 * invL;
    const float yy = 0.8f * v.y * invf + 0.2f * a1 * invL;
    const float yz = 0.8f * v.z * invf + 0.2f * a2 * invL;
    const float yw = 0.8f * v.w * invf + 0.2f * a3 * invL;

    float s2 = yx * yx + yy * yy + yz * yz + yw * yw;
    #pragma unroll
    for (int off = 1; off < 64; off <<= 1) s2 += __shfl_xor(s2, off, 64);
    const float invn = 1.0f / fmaxf(sqrtf(s2), 1e-12f);

    float4 o; o.x = yx * invn; o.y = yy * invn; o.z = yz * invn; o.w = yw * invn;
    *(float4*)(out + (size_t)row * DIM + lane * 4) = o;
}

// ---------------- launcher ----------------
extern "C" void kernel_launch(void* const* d_in, const int* in_sizes, int n_in,
                              void* d_out, int out_size, void* d_ws, size_t ws_size,
                              hipStream_t stream) {
    const float* feats = (const float*)d_in[0];
    float* out = (float*)d_out;
    char* ws = (char*)d_ws;

    // ws: fb fp8 2MB | fv fp8 2MB | Opart bf16 32MB | lpart fp32 256KB
    u8* fb = (u8*)ws;
    u8* fv = (u8*)(ws + (size_t)BN * DIM);
    u16* Op = (u16*)(ws + (size_t)BN * DIM * 2);
    float* lp = (float*)(ws + (size_t)BN * DIM * 2 + (size_t)NSPLIT * BN * DIM * 2);

    k_prep<<<BN / 32, 256, 0, stream>>>(feats, fb, fv);
    k_flash<<<(BN / 128) * NSPLIT, 256, 0, stream>>>(fb, fv, Op, lp);
    k_combine<<<BN / 4, 256, 0, stream>>>(feats, Op, lp, out);
}

// Round 10
// 114.416 us; speedup vs baseline: 2.2140x; 1.0484x over previous
//
#include <hip/hip_runtime.h>

typedef unsigned char u8;
typedef unsigned short u16;
typedef unsigned int u32;
typedef unsigned long long u64;
typedef long long i64;
typedef __attribute__((ext_vector_type(16))) float floatx16;
typedef __attribute__((ext_vector_type(4))) int intx4;
typedef __attribute__((ext_vector_type(8))) int intx8;

#define BN 8192
#define DIM 256
#define NSPLIT 8
#define KPS (BN / NSPLIT)   // 1024 keys per split
#define BKN 64              // keys per barrier period (2 x 32-key QK subtiles)
#define NIT (KPS / BKN)     // 16 iters

__device__ __forceinline__ u16 f2bf(float x) {
    u32 u = __builtin_bit_cast(u32, x);
    u = (u + 0x7fffu + ((u >> 16) & 1u)) >> 16;
    return (u16)u;
}
__device__ __forceinline__ float bf2f(u16 h) {
    return __builtin_bit_cast(float, (u32)h << 16);
}
__device__ __forceinline__ u64 pack4bf(float a, float b, float c, float d) {
    return (u64)f2bf(a) | ((u64)f2bf(b) << 16) | ((u64)f2bf(c) << 32) | ((u64)f2bf(d) << 48);
}
__device__ __forceinline__ u32 pk_fp8(float a, float b, float c, float d) {
    int v = __builtin_amdgcn_cvt_pk_fp8_f32(a, b, 0, false);
    v = __builtin_amdgcn_cvt_pk_fp8_f32(c, d, v, true);
    return (u32)v;
}
__device__ __forceinline__ void gl_lds16(const void* g, void* l) {
    __builtin_amdgcn_global_load_lds(
        (const __attribute__((address_space(1))) u32*)g,
        (__attribute__((address_space(3))) u32*)l, 16, 0, 0);
}
// MX-scaled fp8 MFMA, K=64, unit scales (e8m0 0x7F = 2^0): runs at the MX rate
// (4686 TF ubench = 2.13x the non-scaled fp8 rate). R18 verified QK-side.
#define MFMA64S(A, B, C) __builtin_amdgcn_mfma_scale_f32_32x32x64_f8f6f4( \
        (A), (B), (C), 0, 0, 0, (int)0x7f7f7f7f, 0, (int)0x7f7f7f7f)

// ---------------- kernel 1: row l2-norm -> fp8 fb (row-major) + fp8 fv (V^T tile images) ----
__global__ __launch_bounds__(256) void k_prep(const float* __restrict__ in,
                                              u8* __restrict__ fb, u8* __restrict__ fv) {
    __shared__ u16 t[32 * 260];
    const int tid = threadIdx.x;
    const int wave = tid >> 6, lane = tid & 63;
    const int kb = blockIdx.x, r0 = kb * 32;
    #pragma unroll
    for (int i = 0; i < 8; ++i) {
        const int rl = wave * 8 + i;
        const float4 v = *(const float4*)(in + (size_t)(r0 + rl) * DIM + lane * 4);
        float ss = v.x * v.x + v.y * v.y + v.z * v.z + v.w * v.w;
        #pragma unroll
        for (int off = 1; off < 64; off <<= 1) ss += __shfl_xor(ss, off, 64);
        const float inv = 1.0f / fmaxf(sqrtf(ss), 1e-12f);
        const float n0 = v.x * inv, n1 = v.y * inv, n2 = v.z * inv, n3 = v.w * inv;
        *(u32*)(fb + (size_t)(r0 + rl) * DIM + lane * 4) = pk_fp8(n0, n1, n2, n3);
        *(u64*)(&t[rl * 260 + lane * 4]) = pack4bf(n0, n1, n2, n3);
    }
    __syncthreads();
    #pragma unroll
    for (int i = 0; i < 4; ++i) {
        const int S = i * 256 + tid;              // 8-byte slot index 0..1023
        const int d = S >> 2;
        const int c = ((S & 3) - (d >> 2)) & 3;   // key octet
        float f[8];
        #pragma unroll
        for (int j = 0; j < 8; ++j) f[j] = bf2f(t[(8 * c + j) * 260 + d]);
        const u32 lo = pk_fp8(f[0], f[1], f[2], f[3]);
        const u32 hi = pk_fp8(f[4], f[5], f[6], f[7]);
        *(u64*)(fv + (size_t)kb * 8192 + S * 8) = ((u64)hi << 32) | lo;
    }
}

// ---------------- kernel 2: fp8 flash attention, K=64 MX path for QK AND PV ----------------
// R19 (on R18's 55us base; R18 verified the 2.13x MX rate on QK, prediction
// matched):  PV is now the dominant MFMA cost (589 vs QK 275 cyc/iter/wave).
// Convert PV to mfma_scale_32x32x64 as well:
//  * BKN 32->64: two 32-key QK subtiles per barrier (R17 staging, ran in R8).
//  * P A-frag K=64: lane (q=c31,g1) holds P[q][keys g1*32..+32] = 8 u32 words.
//    Word 2j+half = keys of subtile g1. Own s-rows give crow(r,g1) keys; the
//    interleaving halves come from the partner lane: t_j=shfl(p_j(1)),
//    u_j=shfl(p_j(0)); pa[2j] = g1 ? t_j : p_j(0); pa[2j+1] = g1 ? p_j(1) : u_j.
//  * V B-frag K=64: lane g1 takes subtile g1 (+8192). The fv image's 4 rotated
//    8B chunks per (d-block, c31) = bytes k 0..31 in piece order p=0..3 at
//    chunk (p + (c31>>2))&3 -> 4 x ds_read_b64 per d-block (same op count and
//    alias profile as the old 16 x b64 per 32 keys).
//  * PV: 8 MFMA64S per 64 keys (was 32 x K=16): PV pipe 1178->550 cyc.
__global__ __launch_bounds__(256, 2) void k_flash(
        const u8* __restrict__ fb, const u8* __restrict__ fv,
        u16* __restrict__ Opart, float* __restrict__ lpart) {
    __shared__ u8 tileK[2][16384];  // key-major fp8, chunk-swizzled, 2x32-key subtiles
    __shared__ u8 tileV[2][16384];  // pre-swizzled V^T fp8 images, 2x8KB subtiles

    const int tid = threadIdx.x;
    const int wave = tid >> 6, lane = tid & 63;
    const int c31 = lane & 31, g1 = lane >> 5;
    const int split = blockIdx.x & (NSPLIT - 1);
    const int qblk = blockIdx.x >> 3;
    const int q0 = qblk * 128 + wave * 32;
    const int key0 = split * KPS;

    // Q B-frags for K=64 MFMA (R18-verified layout)
    intx8 qf[4];
    #pragma unroll
    for (int g = 0; g < 4; ++g) {
        const u8* qb = fb + (size_t)(q0 + c31) * DIM + g * 64 + g1 * 32;
        const intx4 lo = *(const intx4*)(qb);
        const intx4 hi = *(const intx4*)(qb + 16);
        qf[g] = __builtin_shufflevector(lo, hi, 0, 1, 2, 3, 4, 5, 6, 7);
    }

    floatx16 o[8];
    #pragma unroll
    for (int i = 0; i < 8; ++i)
        #pragma unroll
        for (int r = 0; r < 16; ++r) o[i][r] = 0.f;
    float lsum = 0.f;

    int offK[4];
    #pragma unroll
    for (int i = 0; i < 4; ++i) {
        const int S = wave * 256 + i * 64 + lane;   // 16B slot 0..1023 (64 key rows)
        const int r = S >> 4, s = S & 15;
        const int c = (s & 8) | ((s ^ r) & 7);
        offK[i] = r * 256 + c * 16;
    }
    const u8* gK = fb + (size_t)key0 * DIM;
    const u8* gV = fv + (size_t)(key0 >> 5) * 8192;

    auto stage = [&](int s, int b) {
        const size_t oo = (size_t)s * 16384;
        u8* lK = &tileK[b][0];
        u8* lV = &tileV[b][0] + wave * 4096;
        #pragma unroll
        for (int i = 0; i < 4; ++i)
            gl_lds16(gK + oo + offK[i], lK + wave * 4096 + i * 1024);
        #pragma unroll
        for (int i = 0; i < 4; ++i)
            gl_lds16(gV + oo + wave * 4096 + i * 1024 + lane * 16, lV + i * 1024);
    };

    // V chunk rotation offsets: piece p lives at chunk (p + (c31>>2)) & 3
    const int rot = c31 >> 2;
    const int co0 = ((rot) & 3) * 8, co1 = ((1 + rot) & 3) * 8;
    const int co2 = ((2 + rot) & 3) * 8, co3 = ((3 + rot) & 3) * 8;

    stage(0, 0);
    for (int it = 0; it < NIT; ++it) {
        const int b = it & 1;
        __syncthreads();                   // drains DMA(it), issued one iter ago
        if (it + 1 < NIT) stage(it + 1, b ^ 1);

        const u8* tk = &tileK[b][0];
        const u8* bk0 = tk + c31 * 256;            // K subtile 0 (keys 0..31)
        const u8* bk1 = tk + 8192 + c31 * 256;     // K subtile 1 (keys 32..63)
        const u8* vbase = &tileV[b][0] + g1 * 8192 + c31 * 32;

        // K A-frag loader (R18-verified): k-group g from subtile base bk
        auto ldk = [&](const u8* bk, int g) -> intx8 {
            const int cw = g * 4 + g1 * 2;
            const int sl = (cw & 8) | ((cw ^ c31) & 7);
            const intx4 lo = *(const intx4*)(bk + sl * 16);
            const intx4 hi = *(const intx4*)(bk + (sl ^ 1) * 16);
            return __builtin_shufflevector(lo, hi, 0, 1, 2, 3, 4, 5, 6, 7);
        };
        // V B-frag loader: d-block ds, 4 rotated 8B pieces -> 8 u32 words
        auto ldv = [&](int ds) -> intx8 {
            const u8* vb = vbase + ds * 1024;
            const i64 v0 = *(const i64*)(vb + co0);
            const i64 v1 = *(const i64*)(vb + co1);
            const i64 v2 = *(const i64*)(vb + co2);
            const i64 v3 = *(const i64*)(vb + co3);
            intx8 r;
            r[0] = (int)v0; r[1] = (int)(v0 >> 32);
            r[2] = (int)v1; r[3] = (int)(v1 >> 32);
            r[4] = (int)v2; r[5] = (int)(v2 >> 32);
            r[6] = (int)v3; r[7] = (int)(v3 >> 32);
            return r;
        };

        floatx16 s0, s1;
        #pragma unroll
        for (int r = 0; r < 16; ++r) { s0[r] = 0.f; s1[r] = 0.f; }

        // ---- QK subtile 0 (keys 0..31), k-frag loads interleaved ----
        intx8 ka0 = ldk(bk0, 0);
        intx8 ka1 = ldk(bk0, 1);
        s0 = MFMA64S(ka0, qf[0], s0); ka0 = ldk(bk0, 2);
        s0 = MFMA64S(ka1, qf[1], s0); ka1 = ldk(bk0, 3);
        s0 = MFMA64S(ka0, qf[2], s0); ka0 = ldk(bk1, 0);
        s0 = MFMA64S(ka1, qf[3], s0); ka1 = ldk(bk1, 1);

        // ---- QK subtile 1 (keys 32..63), exp(s0) interleaved ----
        s1 = MFMA64S(ka0, qf[0], s1);
        const float f00 = __expf(s0[0]), f01 = __expf(s0[1]), f02 = __expf(s0[2]), f03 = __expf(s0[3]);
        const float f04 = __expf(s0[4]), f05 = __expf(s0[5]), f06 = __expf(s0[6]), f07 = __expf(s0[7]);
        ka0 = ldk(bk1, 2);
        s1 = MFMA64S(ka1, qf[1], s1);
        const float f08 = __expf(s0[8]), f09 = __expf(s0[9]), f10 = __expf(s0[10]), f11 = __expf(s0[11]);
        const float f12 = __expf(s0[12]), f13 = __expf(s0[13]), f14 = __expf(s0[14]), f15 = __expf(s0[15]);
        ka1 = ldk(bk1, 3);
        s1 = MFMA64S(ka0, qf[2], s1);
        const u32 pA0 = pk_fp8(f00, f01, f02, f03);
        const u32 pA1 = pk_fp8(f04, f05, f06, f07);
        const u32 pA2 = pk_fp8(f08, f09, f10, f11);
        const u32 pA3 = pk_fp8(f12, f13, f14, f15);
        lsum += ((f00 + f01) + (f02 + f03)) + ((f04 + f05) + (f06 + f07));
        lsum += ((f08 + f09) + (f10 + f11)) + ((f12 + f13) + (f14 + f15));
        s1 = MFMA64S(ka1, qf[3], s1);

        // ---- exp(s1) -> p(1); assemble K=64 P A-frag ----
        const float g00 = __expf(s1[0]), g01 = __expf(s1[1]), g02 = __expf(s1[2]), g03 = __expf(s1[3]);
        const float g04 = __expf(s1[4]), g05 = __expf(s1[5]), g06 = __expf(s1[6]), g07 = __expf(s1[7]);
        const float g08 = __expf(s1[8]), g09 = __expf(s1[9]), g10 = __expf(s1[10]), g11 = __expf(s1[11]);
        const float g12 = __expf(s1[12]), g13 = __expf(s1[13]), g14 = __expf(s1[14]), g15 = __expf(s1[15]);
        const u32 pB0 = pk_fp8(g00, g01, g02, g03);
        const u32 pB1 = pk_fp8(g04, g05, g06, g07);
        const u32 pB2 = pk_fp8(g08, g09, g10, g11);
        const u32 pB3 = pk_fp8(g12, g13, g14, g15);
        lsum += ((g00 + g01) + (g02 + g03)) + ((g04 + g05) + (g06 + g07));
        lsum += ((g08 + g09) + (g10 + g11)) + ((g12 + g13) + (g14 + g15));

        // pa[2j]   = g1 ? shfl(pB_j) : pA_j   (even words: subtile-g1, crow(.,0) keys)
        // pa[2j+1] = g1 ? pB_j : shfl(pA_j)   (odd words:  subtile-g1, crow(.,1) keys)
        const u32 tB0 = (u32)__shfl_xor((int)pB0, 32, 64);
        const u32 uA0 = (u32)__shfl_xor((int)pA0, 32, 64);
        const u32 tB1 = (u32)__shfl_xor((int)pB1, 32, 64);
        const u32 uA1 = (u32)__shfl_xor((int)pA1, 32, 64);
        const u32 tB2 = (u32)__shfl_xor((int)pB2, 32, 64);
        const u32 uA2 = (u32)__shfl_xor((int)pA2, 32, 64);
        const u32 tB3 = (u32)__shfl_xor((int)pB3, 32, 64);
        const u32 uA3 = (u32)__shfl_xor((int)pA3, 32, 64);
        intx8 PA;
        PA[0] = (int)(g1 ? tB0 : pA0); PA[1] = (int)(g1 ? pB0 : uA0);
        PA[2] = (int)(g1 ? tB1 : pA1); PA[3] = (int)(g1 ? pB1 : uA1);
        PA[4] = (int)(g1 ? tB2 : pA2); PA[5] = (int)(g1 ? pB2 : uA2);
        PA[6] = (int)(g1 ? tB3 : pA3); PA[7] = (int)(g1 ? pB3 : uA3);

        // ---- PV: 8 x K=64 MFMAs, V-frag loads pipelined 2 deep ----
        intx8 v0 = ldv(0), v1 = ldv(1);
        o[0] = MFMA64S(PA, v0, o[0]); v0 = ldv(2);
        o[1] = MFMA64S(PA, v1, o[1]); v1 = ldv(3);
        o[2] = MFMA64S(PA, v0, o[2]); v0 = ldv(4);
        o[3] = MFMA64S(PA, v1, o[3]); v1 = ldv(5);
        o[4] = MFMA64S(PA, v0, o[4]); v0 = ldv(6);
        o[5] = MFMA64S(PA, v1, o[5]); v1 = ldv(7);
        o[6] = MFMA64S(PA, v0, o[6]);
        o[7] = MFMA64S(PA, v1, o[7]);
    }

    // ---- epilogue: bf16 partial O + fp32 partial l ----
    u16* ob = Opart + ((size_t)split * BN + q0) * DIM;
    #pragma unroll
    for (int ds = 0; ds < 8; ++ds) {
        #pragma unroll
        for (int r = 0; r < 16; ++r) {
            const int ql = (r & 3) + 8 * (r >> 2) + 4 * g1;
            ob[(size_t)ql * DIM + ds * 32 + c31] = f2bf(o[ds][r]);
        }
    }
    lsum += __shfl_xor(lsum, 32, 64);
    if (g1 == 0) lpart[(size_t)split * BN + q0 + c31] = lsum;
}

// ---------------- kernel 3: merge splits, blend, final l2-normalize ----------------
__global__ __launch_bounds__(256) void k_combine(
        const float* __restrict__ feats, const u16* __restrict__ Opart,
        const float* __restrict__ lpart, float* __restrict__ out) {
    const int row = blockIdx.x * 4 + (threadIdx.x >> 6);
    const int lane = threadIdx.x & 63;

    float L = 0.f;
    #pragma unroll
    for (int s = 0; s < NSPLIT; ++s) L += lpart[(size_t)s * BN + row];

    float a0 = 0.f, a1 = 0.f, a2 = 0.f, a3 = 0.f;
    #pragma unroll
    for (int s = 0; s < NSPLIT; ++s) {
        const ushort4 o = *(const ushort4*)(Opart + ((size_t)s * BN + row) * DIM + lane * 4);
        a0 += bf2f(o.x); a1 += bf2f(o.y); a2 += bf2f(o.z); a3 += bf2f(o.w);
    }
    const float invL = 1.0f / L;

    const float4 v = *(const float4*)(feats + (size_t)row * DIM + lane * 4);
    float ss = v.x * v.x + v.y * v.y + v.z * v.z + v.w * v.w;
    #pragma unroll
    for (int off = 1; off < 64; off <<= 1) ss += __shfl_xor(ss, off, 64);
    const float invf = 1.0f / fmaxf(sqrtf(ss), 1e-12f);

    const float yx = 0.8f * v.x * invf + 0.2f * a0 * invL;
    const float yy = 0.8f * v.y * invf + 0.2f * a1 * invL;
    const float yz = 0.8f * v.z * invf + 0.2f * a2 * invL;
    const float yw = 0.8f * v.w * invf + 0.2f * a3 * invL;

    float s2 = yx * yx + yy * yy + yz * yz + yw * yw;
    #pragma unroll
    for (int off = 1; off < 64; off <<= 1) s2 += __shfl_xor(s2, off, 64);
    const float invn = 1.0f / fmaxf(sqrtf(s2), 1e-12f);

    float4 o; o.x = yx * invn; o.y = yy * invn; o.z = yz * invn; o.w = yw * invn;
    *(float4*)(out + (size_t)row * DIM + lane * 4) = o;
}

// ---------------- launcher ----------------
extern "C" void kernel_launch(void* const* d_in, const int* in_sizes, int n_in,
                              void* d_out, int out_size, void* d_ws, size_t ws_size,
                              hipStream_t stream) {
    const float* feats = (const float*)d_in[0];
    float* out = (float*)d_out;
    char* ws = (char*)d_ws;

    // ws: fb fp8 2MB | fv fp8 2MB | Opart bf16 32MB | lpart fp32 256KB
    u8* fb = (u8*)ws;
    u8* fv = (u8*)(ws + (size_t)BN * DIM);
    u16* Op = (u16*)(ws + (size_t)BN * DIM * 2);
    float* lp = (float*)(ws + (size_t)BN * DIM * 2 + (size_t)NSPLIT * BN * DIM * 2);

    k_prep<<<BN / 32, 256, 0, stream>>>(feats, fb, fv);
    k_flash<<<(BN / 128) * NSPLIT, 256, 0, stream>>>(fb, fv, Op, lp);
    k_combine<<<BN / 4, 256, 0, stream>>>(feats, Op, lp, out);
}

// Round 12
// 112.909 us; speedup vs baseline: 2.2436x; 1.0133x over previous
//
#include <hip/hip_runtime.h>

typedef unsigned char u8;
typedef unsigned short u16;
typedef unsigned int u32;
typedef unsigned long long u64;
typedef long long i64;
typedef __attribute__((ext_vector_type(16))) float floatx16;
typedef __attribute__((ext_vector_type(4))) int intx4;
typedef __attribute__((ext_vector_type(8))) int intx8;

#define BN 8192
#define DIM 256
#define NSPLIT 8
#define KPS (BN / NSPLIT)   // 1024 keys per split
#define BKN 64              // keys per barrier period (2 x 32-key QK subtiles)
#define NIT (KPS / BKN)     // 16 iters

__device__ __forceinline__ u16 f2bf(float x) {
    u32 u = __builtin_bit_cast(u32, x);
    u = (u + 0x7fffu + ((u >> 16) & 1u)) >> 16;
    return (u16)u;
}
__device__ __forceinline__ float bf2f(u16 h) {
    return __builtin_bit_cast(float, (u32)h << 16);
}
__device__ __forceinline__ u64 pack4bf(float a, float b, float c, float d) {
    return (u64)f2bf(a) | ((u64)f2bf(b) << 16) | ((u64)f2bf(c) << 32) | ((u64)f2bf(d) << 48);
}
__device__ __forceinline__ u32 pk_fp8(float a, float b, float c, float d) {
    int v = __builtin_amdgcn_cvt_pk_fp8_f32(a, b, 0, false);
    v = __builtin_amdgcn_cvt_pk_fp8_f32(c, d, v, true);
    return (u32)v;
}
__device__ __forceinline__ void gl_lds16(const void* g, void* l) {
    __builtin_amdgcn_global_load_lds(
        (const __attribute__((address_space(1))) u32*)g,
        (__attribute__((address_space(3))) u32*)l, 16, 0, 0);
}
// MX-scaled fp8 MFMA, K=64, unit scales (e8m0 0x7F = 2^0): runs at the MX rate
// (4686 TF ubench = 2.13x the non-scaled fp8 rate). R18/R19 verified both sides.
#define MFMA64S(A, B, C) __builtin_amdgcn_mfma_scale_f32_32x32x64_f8f6f4( \
        (A), (B), (C), 0, 0, 0, (int)0x7f7f7f7f, 0, (int)0x7f7f7f7f)

// ---------------- kernel 1: row l2-norm -> fp8 fb (row-major) + fp8 fv (V^T tile images) ----
__global__ __launch_bounds__(256) void k_prep(const float* __restrict__ in,
                                              u8* __restrict__ fb, u8* __restrict__ fv) {
    __shared__ u16 t[32 * 260];
    const int tid = threadIdx.x;
    const int wave = tid >> 6, lane = tid & 63;
    const int kb = blockIdx.x, r0 = kb * 32;
    #pragma unroll
    for (int i = 0; i < 8; ++i) {
        const int rl = wave * 8 + i;
        const float4 v = *(const float4*)(in + (size_t)(r0 + rl) * DIM + lane * 4);
        float ss = v.x * v.x + v.y * v.y + v.z * v.z + v.w * v.w;
        #pragma unroll
        for (int off = 1; off < 64; off <<= 1) ss += __shfl_xor(ss, off, 64);
        const float inv = 1.0f / fmaxf(sqrtf(ss), 1e-12f);
        const float n0 = v.x * inv, n1 = v.y * inv, n2 = v.z * inv, n3 = v.w * inv;
        *(u32*)(fb + (size_t)(r0 + rl) * DIM + lane * 4) = pk_fp8(n0, n1, n2, n3);
        *(u64*)(&t[rl * 260 + lane * 4]) = pack4bf(n0, n1, n2, n3);
    }
    __syncthreads();
    #pragma unroll
    for (int i = 0; i < 4; ++i) {
        const int S = i * 256 + tid;              // 8-byte slot index 0..1023
        const int d = S >> 2;
        const int c = ((S & 3) - (d >> 2)) & 3;   // key octet
        float f[8];
        #pragma unroll
        for (int j = 0; j < 8; ++j) f[j] = bf2f(t[(8 * c + j) * 260 + d]);
        const u32 lo = pk_fp8(f[0], f[1], f[2], f[3]);
        const u32 hi = pk_fp8(f[4], f[5], f[6], f[7]);
        *(u64*)(fv + (size_t)kb * 8192 + S * 8) = ((u64)hi << 32) | lo;
    }
}

// ---------------- kernel 2: fp8 flash attention, K=64 MX path for QK AND PV ----------------
// R20 resubmit (R11 bench was an infra failure; kernel never ran).
// On R19's 49.8us base:
//  * CORRECT de-phase: co-resident block pair on a CU is (i, i+256); split
//    (bits 0-2) and qblk parity are IDENTICAL within the pair (256%8==0,
//    qblk diff 32 even) -> every earlier stagger key (R8: split&1) was
//    constant across the pair and shifted nothing. Bit 8 of blockIdx is
//    exactly what flips between i and i+256: sleep ~1.5k cyc (~1/4 iter)
//    so one block's MFMA clusters overlay the other's exp/VALU phases
//    (pipe sums = 75-80% < wall -> ~20-25% simultaneous-stall gap).
//  * setprio(1) around MFMA clusters: T5 requires phase diversity; it was
//    correctly null in phase-locked R8, should pay in the de-phased regime.
//  * Everything else identical to R19 (QK+PV both mfma_scale_32x32x64).
__global__ __launch_bounds__(256, 2) void k_flash(
        const u8* __restrict__ fb, const u8* __restrict__ fv,
        u16* __restrict__ Opart, float* __restrict__ lpart) {
    __shared__ u8 tileK[2][16384];  // key-major fp8, chunk-swizzled, 2x32-key subtiles
    __shared__ u8 tileV[2][16384];  // pre-swizzled V^T fp8 images, 2x8KB subtiles

    const int tid = threadIdx.x;
    const int wave = tid >> 6, lane = tid & 63;
    const int c31 = lane & 31, g1 = lane >> 5;
    const int split = blockIdx.x & (NSPLIT - 1);
    const int qblk = blockIdx.x >> 3;
    const int q0 = qblk * 128 + wave * 32;
    const int key0 = split * KPS;

    // Q B-frags for K=64 MFMA (R18-verified layout)
    intx8 qf[4];
    #pragma unroll
    for (int g = 0; g < 4; ++g) {
        const u8* qb = fb + (size_t)(q0 + c31) * DIM + g * 64 + g1 * 32;
        const intx4 lo = *(const intx4*)(qb);
        const intx4 hi = *(const intx4*)(qb + 16);
        qf[g] = __builtin_shufflevector(lo, hi, 0, 1, 2, 3, 4, 5, 6, 7);
    }

    floatx16 o[8];
    #pragma unroll
    for (int i = 0; i < 8; ++i)
        #pragma unroll
        for (int r = 0; r < 16; ++r) o[i][r] = 0.f;
    float lsum = 0.f;

    int offK[4];
    #pragma unroll
    for (int i = 0; i < 4; ++i) {
        const int S = wave * 256 + i * 64 + lane;   // 16B slot 0..1023 (64 key rows)
        const int r = S >> 4, s = S & 15;
        const int c = (s & 8) | ((s ^ r) & 7);
        offK[i] = r * 256 + c * 16;
    }
    const u8* gK = fb + (size_t)key0 * DIM;
    const u8* gV = fv + (size_t)(key0 >> 5) * 8192;

    auto stage = [&](int s, int b) {
        const size_t oo = (size_t)s * 16384;
        u8* lK = &tileK[b][0];
        u8* lV = &tileV[b][0] + wave * 4096;
        #pragma unroll
        for (int i = 0; i < 4; ++i)
            gl_lds16(gK + oo + offK[i], lK + wave * 4096 + i * 1024);
        #pragma unroll
        for (int i = 0; i < 4; ++i)
            gl_lds16(gV + oo + wave * 4096 + i * 1024 + lane * 16, lV + i * 1024);
    };

    // V chunk rotation offsets: piece p lives at chunk (p + (c31>>2)) & 3
    const int rot = c31 >> 2;
    const int co0 = ((rot) & 3) * 8, co1 = ((1 + rot) & 3) * 8;
    const int co2 = ((2 + rot) & 3) * 8, co3 = ((3 + rot) & 3) * 8;

    stage(0, 0);
    // de-phase the co-resident pair: bit 8 flips between block i and i+256
    if ((blockIdx.x >> 8) & 1) __builtin_amdgcn_s_sleep(24);   // ~1536 cyc, once

    for (int it = 0; it < NIT; ++it) {
        const int b = it & 1;
        __syncthreads();                   // drains DMA(it), issued one iter ago
        if (it + 1 < NIT) stage(it + 1, b ^ 1);

        const u8* tk = &tileK[b][0];
        const u8* bk0 = tk + c31 * 256;            // K subtile 0 (keys 0..31)
        const u8* bk1 = tk + 8192 + c31 * 256;     // K subtile 1 (keys 32..63)
        const u8* vbase = &tileV[b][0] + g1 * 8192 + c31 * 32;

        // K A-frag loader (R18-verified): k-group g from subtile base bk
        auto ldk = [&](const u8* bk, int g) -> intx8 {
            const int cw = g * 4 + g1 * 2;
            const int sl = (cw & 8) | ((cw ^ c31) & 7);
            const intx4 lo = *(const intx4*)(bk + sl * 16);
            const intx4 hi = *(const intx4*)(bk + (sl ^ 1) * 16);
            return __builtin_shufflevector(lo, hi, 0, 1, 2, 3, 4, 5, 6, 7);
        };
        // V B-frag loader: d-block ds, 4 rotated 8B pieces -> 8 u32 words
        auto ldv = [&](int ds) -> intx8 {
            const u8* vb = vbase + ds * 1024;
            const i64 v0 = *(const i64*)(vb + co0);
            const i64 v1 = *(const i64*)(vb + co1);
            const i64 v2 = *(const i64*)(vb + co2);
            const i64 v3 = *(const i64*)(vb + co3);
            intx8 r;
            r[0] = (int)v0; r[1] = (int)(v0 >> 32);
            r[2] = (int)v1; r[3] = (int)(v1 >> 32);
            r[4] = (int)v2; r[5] = (int)(v2 >> 32);
            r[6] = (int)v3; r[7] = (int)(v3 >> 32);
            return r;
        };

        floatx16 s0, s1;
        #pragma unroll
        for (int r = 0; r < 16; ++r) { s0[r] = 0.f; s1[r] = 0.f; }

        // ---- QK subtile 0 (keys 0..31), k-frag loads interleaved ----
        intx8 ka0 = ldk(bk0, 0);
        intx8 ka1 = ldk(bk0, 1);
        __builtin_amdgcn_s_setprio(1);
        s0 = MFMA64S(ka0, qf[0], s0); ka0 = ldk(bk0, 2);
        s0 = MFMA64S(ka1, qf[1], s0); ka1 = ldk(bk0, 3);
        s0 = MFMA64S(ka0, qf[2], s0); ka0 = ldk(bk1, 0);
        s0 = MFMA64S(ka1, qf[3], s0); ka1 = ldk(bk1, 1);
        __builtin_amdgcn_s_setprio(0);

        // ---- QK subtile 1 (keys 32..63), exp(s0) interleaved ----
        __builtin_amdgcn_s_setprio(1);
        s1 = MFMA64S(ka0, qf[0], s1);
        const float f00 = __expf(s0[0]), f01 = __expf(s0[1]), f02 = __expf(s0[2]), f03 = __expf(s0[3]);
        const float f04 = __expf(s0[4]), f05 = __expf(s0[5]), f06 = __expf(s0[6]), f07 = __expf(s0[7]);
        ka0 = ldk(bk1, 2);
        s1 = MFMA64S(ka1, qf[1], s1);
        const float f08 = __expf(s0[8]), f09 = __expf(s0[9]), f10 = __expf(s0[10]), f11 = __expf(s0[11]);
        const float f12 = __expf(s0[12]), f13 = __expf(s0[13]), f14 = __expf(s0[14]), f15 = __expf(s0[15]);
        ka1 = ldk(bk1, 3);
        s1 = MFMA64S(ka0, qf[2], s1);
        const u32 pA0 = pk_fp8(f00, f01, f02, f03);
        const u32 pA1 = pk_fp8(f04, f05, f06, f07);
        const u32 pA2 = pk_fp8(f08, f09, f10, f11);
        const u32 pA3 = pk_fp8(f12, f13, f14, f15);
        lsum += ((f00 + f01) + (f02 + f03)) + ((f04 + f05) + (f06 + f07));
        lsum += ((f08 + f09) + (f10 + f11)) + ((f12 + f13) + (f14 + f15));
        s1 = MFMA64S(ka1, qf[3], s1);
        __builtin_amdgcn_s_setprio(0);

        // ---- exp(s1) -> p(1); assemble K=64 P A-frag ----
        const float g00 = __expf(s1[0]), g01 = __expf(s1[1]), g02 = __expf(s1[2]), g03 = __expf(s1[3]);
        const float g04 = __expf(s1[4]), g05 = __expf(s1[5]), g06 = __expf(s1[6]), g07 = __expf(s1[7]);
        const float g08 = __expf(s1[8]), g09 = __expf(s1[9]), g10 = __expf(s1[10]), g11 = __expf(s1[11]);
        const float g12 = __expf(s1[12]), g13 = __expf(s1[13]), g14 = __expf(s1[14]), g15 = __expf(s1[15]);
        const u32 pB0 = pk_fp8(g00, g01, g02, g03);
        const u32 pB1 = pk_fp8(g04, g05, g06, g07);
        const u32 pB2 = pk_fp8(g08, g09, g10, g11);
        const u32 pB3 = pk_fp8(g12, g13, g14, g15);
        lsum += ((g00 + g01) + (g02 + g03)) + ((g04 + g05) + (g06 + g07));
        lsum += ((g08 + g09) + (g10 + g11)) + ((g12 + g13) + (g14 + g15));

        // pa[2j]   = g1 ? shfl(pB_j) : pA_j   (even words: subtile-g1, crow(.,0) keys)
        // pa[2j+1] = g1 ? pB_j : shfl(pA_j)   (odd words:  subtile-g1, crow(.,1) keys)
        const u32 tB0 = (u32)__shfl_xor((int)pB0, 32, 64);
        const u32 uA0 = (u32)__shfl_xor((int)pA0, 32, 64);
        const u32 tB1 = (u32)__shfl_xor((int)pB1, 32, 64);
        const u32 uA1 = (u32)__shfl_xor((int)pA1, 32, 64);
        const u32 tB2 = (u32)__shfl_xor((int)pB2, 32, 64);
        const u32 uA2 = (u32)__shfl_xor((int)pA2, 32, 64);
        const u32 tB3 = (u32)__shfl_xor((int)pB3, 32, 64);
        const u32 uA3 = (u32)__shfl_xor((int)pA3, 32, 64);
        intx8 PA;
        PA[0] = (int)(g1 ? tB0 : pA0); PA[1] = (int)(g1 ? pB0 : uA0);
        PA[2] = (int)(g1 ? tB1 : pA1); PA[3] = (int)(g1 ? pB1 : uA1);
        PA[4] = (int)(g1 ? tB2 : pA2); PA[5] = (int)(g1 ? pB2 : uA2);
        PA[6] = (int)(g1 ? tB3 : pA3); PA[7] = (int)(g1 ? pB3 : uA3);

        // ---- PV: 8 x K=64 MFMAs, V-frag loads pipelined 2 deep ----
        intx8 v0 = ldv(0), v1 = ldv(1);
        __builtin_amdgcn_s_setprio(1);
        o[0] = MFMA64S(PA, v0, o[0]); v0 = ldv(2);
        o[1] = MFMA64S(PA, v1, o[1]); v1 = ldv(3);
        o[2] = MFMA64S(PA, v0, o[2]); v0 = ldv(4);
        o[3] = MFMA64S(PA, v1, o[3]); v1 = ldv(5);
        o[4] = MFMA64S(PA, v0, o[4]); v0 = ldv(6);
        o[5] = MFMA64S(PA, v1, o[5]); v1 = ldv(7);
        o[6] = MFMA64S(PA, v0, o[6]);
        o[7] = MFMA64S(PA, v1, o[7]);
        __builtin_amdgcn_s_setprio(0);
    }

    // ---- epilogue: bf16 partial O + fp32 partial l ----
    u16* ob = Opart + ((size_t)split * BN + q0) * DIM;
    #pragma unroll
    for (int ds = 0; ds < 8; ++ds) {
        #pragma unroll
        for (int r = 0; r < 16; ++r) {
            const int ql = (r & 3) + 8 * (r >> 2) + 4 * g1;
            ob[(size_t)ql * DIM + ds * 32 + c31] = f2bf(o[ds][r]);
        }
    }
    lsum += __shfl_xor(lsum, 32, 64);
    if (g1 == 0) lpart[(size_t)split * BN + q0 + c31] = lsum;
}

// ---------------- kernel 3: merge splits, blend, final l2-normalize ----------------
__global__ __launch_bounds__(256) void k_combine(
        const float* __restrict__ feats, const u16* __restrict__ Opart,
        const float* __restrict__ lpart, float* __restrict__ out) {
    const int row = blockIdx.x * 4 + (threadIdx.x >> 6);
    const int lane = threadIdx.x & 63;

    float L = 0.f;
    #pragma unroll
    for (int s = 0; s < NSPLIT; ++s) L += lpart[(size_t)s * BN + row];

    float a0 = 0.f, a1 = 0.f, a2 = 0.f, a3 = 0.f;
    #pragma unroll
    for (int s = 0; s < NSPLIT; ++s) {
        const ushort4 o = *(const ushort4*)(Opart + ((size_t)s * BN + row) * DIM + lane * 4);
        a0 += bf2f(o.x); a1 += bf2f(o.y); a2 += bf2f(o.z); a3 += bf2f(o.w);
    }
    const float invL = 1.0f / L;

    const float4 v = *(const float4*)(feats + (size_t)row * DIM + lane * 4);
    float ss = v.x * v.x + v.y * v.y + v.z * v.z + v.w * v.w;
    #pragma unroll
    for (int off = 1; off < 64; off <<= 1) ss += __shfl_xor(ss, off, 64);
    const float invf = 1.0f / fmaxf(sqrtf(ss), 1e-12f);

    const float yx = 0.8f * v.x * invf + 0.2f * a0 * invL;
    const float yy = 0.8f * v.y * invf + 0.2f * a1 * invL;
    const float yz = 0.8f * v.z * invf + 0.2f * a2 * invL;
    const float yw = 0.8f * v.w * invf + 0.2f * a3 * invL;

    float s2 = yx * yx + yy * yy + yz * yz + yw * yw;
    #pragma unroll
    for (int off = 1; off < 64; off <<= 1) s2 += __shfl_xor(s2, off, 64);
    const float invn = 1.0f / fmaxf(sqrtf(s2), 1e-12f);

    float4 o; o.x = yx * invn; o.y = yy * invn; o.z = yz * invn; o.w = yw * invn;
    *(float4*)(out + (size_t)row * DIM + lane * 4) = o;
}

// ---------------- launcher ----------------
extern "C" void kernel_launch(void* const* d_in, const int* in_sizes, int n_in,
                              void* d_out, int out_size, void* d_ws, size_t ws_size,
                              hipStream_t stream) {
    const float* feats = (const float*)d_in[0];
    float* out = (float*)d_out;
    char* ws = (char*)d_ws;

    // ws: fb fp8 2MB | fv fp8 2MB | Opart bf16 32MB | lpart fp32 256KB
    u8* fb = (u8*)ws;
    u8* fv = (u8*)(ws + (size_t)BN * DIM);
    u16* Op = (u16*)(ws + (size_t)BN * DIM * 2);
    float* lp = (float*)(ws + (size_t)BN * DIM * 2 + (size_t)NSPLIT * BN * DIM * 2);

    k_prep<<<BN / 32, 256, 0, stream>>>(feats, fb, fv);
    k_flash<<<(BN / 128) * NSPLIT, 256, 0, stream>>>(fb, fv, Op, lp);
    k_combine<<<BN / 4, 256, 0, stream>>>(feats, Op, lp, out);
}